// Round 2
// baseline (149.181 us; speedup 1.0000x reference)
//
#include <hip/hip_runtime.h>

typedef __bf16 bf16_t;
typedef bf16_t bf16x8 __attribute__((ext_vector_type(8)));
typedef bf16_t bf16x4 __attribute__((ext_vector_type(4)));
typedef float f32x4 __attribute__((ext_vector_type(4)));

#define M_TOK 32768
#define NWIN 128
#define WIN  256

typedef __attribute__((address_space(3))) void* as3p;
typedef const __attribute__((address_space(1))) void* as1p;

__device__ __forceinline__ void gll16(const void* g, void* l) {
    __builtin_amdgcn_global_load_lds((as1p)g, (as3p)l, 16, 0, 0);
}

__device__ __forceinline__ bf16x8 cvt8(f32x4 a, f32x4 b) {
    bf16x8 o;
    o[0] = (bf16_t)a[0]; o[1] = (bf16_t)a[1]; o[2] = (bf16_t)a[2]; o[3] = (bf16_t)a[3];
    o[4] = (bf16_t)b[0]; o[5] = (bf16_t)b[1]; o[6] = (bf16_t)b[2]; o[7] = (bf16_t)b[3];
    return o;
}

// tiny fp32->bf16 weight convert (w_qkv 196608 + w_proj 65536 elems)
__global__ __launch_bounds__(256) void wconv(
    const float* __restrict__ wq, const float* __restrict__ wp,
    bf16_t* __restrict__ wqb, bf16_t* __restrict__ wpb)
{
    int i4 = (blockIdx.x * 256 + threadIdx.x) * 4;
    const float* s; bf16_t* dst; int idx;
    if (i4 < 196608) { s = wq; dst = wqb; idx = i4; }
    else             { s = wp; dst = wpb; idx = i4 - 196608; }
    f32x4 v = *(const f32x4*)(s + idx);
    bf16x4 o;
    o[0] = (bf16_t)v[0]; o[1] = (bf16_t)v[1]; o[2] = (bf16_t)v[2]; o[3] = (bf16_t)v[3];
    *(bf16x4*)(dst + idx) = o;
}

// GEMM1: QKV = relu_qk(X @ Wqkv^T). X fp32 [32768,256] (converted in-kernel),
// W bf16 [768,256]. Output QKV[nblk][tok][32], nblk = n>>5 (0..7 q, 8..15 k, 16..23 v).
// Double-buffered 2-phase pipeline (T3-minimum): stage(t+1) issued before compute(t),
// one barrier per K-iter (implicit vmcnt/lgkm drain at __syncthreads).
// LDS rows 64B, XOR swizzle col = g ^ ((row>>1)&3) -> 2-way (free) fragment reads.
__global__ __launch_bounds__(256) void gemm1_qkv(
    const float* __restrict__ X,
    const bf16_t* __restrict__ Wb,
    bf16_t* __restrict__ QKV)
{
    __shared__ __align__(16) bf16_t As[2][128][32];
    __shared__ __align__(16) bf16_t Bs[2][128][32];

    const int tid = threadIdx.x;
    const int lane = tid & 63;
    const int wv = tid >> 6;
    const int wm = wv >> 1, wn = wv & 1;
    // supertile swizzle: 8 m-blocks x 6 n-blocks share A/B panels in L2
    const int id = blockIdx.x;
    const int sg = id / 48, wsub = id % 48;
    const int m0 = (sg * 8 + (wsub & 7)) * 128;
    const int n0 = (wsub >> 3) * 128;
    const int r = lane & 15, q = lane >> 4;
    const int lrow = lane >> 2;                          // 0..15 row within 1KB unit
    const int lcol = lane & 3;                           // granule column
    const int sgr = (lcol ^ ((lane >> 3) & 3)) * 8;      // pre-swizzled src k-offset
    const int ax8 = (q ^ ((r >> 1) & 3)) * 8;            // read-side swizzled granule

    f32x4 acc[4][4] = {};

    // A: reg-staged fp32 -> cvt -> swizzled ds_write.  B: gll16 pre-swizzled src.
    auto loadA = [&](int kc, f32x4 (&ar)[2][2]) {
#pragma unroll
        for (int g = 0; g < 2; ++g) {
            const float* src = X + (size_t)(m0 + wv * 32 + g * 16 + lrow) * 256 + kc + sgr;
            ar[g][0] = *(const f32x4*)src;
            ar[g][1] = *(const f32x4*)(src + 4);
        }
    };
    auto stageB = [&](int kc, int buf) {
#pragma unroll
        for (int g = 0; g < 2; ++g)
            gll16(Wb + (size_t)(n0 + wv * 32 + g * 16 + lrow) * 256 + kc + sgr,
                  &Bs[buf][wv * 32 + g * 16][0]);
    };
    auto writeA = [&](f32x4 (&ar)[2][2], int buf) {
#pragma unroll
        for (int g = 0; g < 2; ++g)
            *(bf16x8*)&As[buf][wv * 32 + g * 16 + lrow][lcol * 8] = cvt8(ar[g][0], ar[g][1]);
    };
    auto compute = [&](int buf) {
        bf16x8 a[4], b[4];
#pragma unroll
        for (int i = 0; i < 4; ++i)
            a[i] = *(const bf16x8*)&As[buf][wm * 64 + i * 16 + r][ax8];
#pragma unroll
        for (int j = 0; j < 4; ++j)
            b[j] = *(const bf16x8*)&Bs[buf][wn * 64 + j * 16 + r][ax8];
#pragma unroll
        for (int i = 0; i < 4; ++i)
#pragma unroll
            for (int j = 0; j < 4; ++j)   // swapped: col-field->m(r), row-field->n(q*4+reg)
                acc[i][j] = __builtin_amdgcn_mfma_f32_16x16x32_bf16(b[j], a[i], acc[i][j], 0, 0, 0);
    };

    {   // prologue: stage K-step 0 into buf 0
        f32x4 ar[2][2];
        loadA(0, ar);
        stageB(0, 0);
        writeA(ar, 0);
    }
    __syncthreads();

#pragma unroll
    for (int t = 0; t < 7; ++t) {
        const int cur = t & 1, nxt = cur ^ 1;
        f32x4 ar[2][2];
        loadA((t + 1) * 32, ar);       // issue next A loads (latency hides under MFMA)
        stageB((t + 1) * 32, nxt);     // issue next B DMA
        compute(cur);
        writeA(ar, nxt);               // compiler waits vmcnt for ar just before use
        __syncthreads();               // drains gll16 (vmcnt) + ds_write (lgkm)
    }
    compute(1);                        // t = 7

#pragma unroll
    for (int i = 0; i < 4; ++i) {
        const int rowg = m0 + wm * 64 + i * 16 + r;
#pragma unroll
        for (int j = 0; j < 4; ++j) {
            const int nb = n0 + wn * 64 + j * 16 + q * 4;
            const int nblk = nb >> 5, d = nb & 31;
            bf16x4 o;
#pragma unroll
            for (int reg = 0; reg < 4; ++reg) {
                float v = acc[i][j][reg];
                if (nblk < 16) v = fmaxf(v, 0.0f);   // relu on q,k (n<512)
                o[reg] = (bf16_t)v;
            }
            *(bf16x4*)&QKV[((size_t)nblk * M_TOK + rowg) * 32 + d] = o;
        }
    }
}

// GEMM2: Out = Y @ Wproj^T + b, Y bf16 [32768,256], Out fp32.
// Tile 128x64, double-buffered 2-phase pipeline, 24KB LDS -> 6 blocks/CU.
__global__ __launch_bounds__(256) void gemm2_proj(
    const bf16_t* __restrict__ Y,
    const bf16_t* __restrict__ Wb,
    const float* __restrict__ bias,
    float* __restrict__ Out)
{
    __shared__ __align__(16) bf16_t As[2][128][32];
    __shared__ __align__(16) bf16_t Bs[2][64][32];

    const int tid = threadIdx.x;
    const int lane = tid & 63;
    const int wv = tid >> 6;
    const int wm = wv >> 1, wn = wv & 1;
    const int id = blockIdx.x;
    const int sg = id / 32, wsub = id % 32;      // supertile: 8m x 4n
    const int m0 = (sg * 8 + (wsub & 7)) * 128;
    const int n0 = (wsub >> 3) * 64;
    const int r = lane & 15, q = lane >> 4;
    const int lrow = lane >> 2;
    const int sgr = ((lane & 3) ^ ((lane >> 3) & 3)) * 8;
    const int ax8 = (q ^ ((r >> 1) & 3)) * 8;

    f32x4 acc[4][2] = {};

    auto stage = [&](int kc, int buf) {
#pragma unroll
        for (int g = 0; g < 2; ++g)
            gll16(Y + (size_t)(m0 + wv * 32 + g * 16 + lrow) * 256 + kc + sgr,
                  &As[buf][wv * 32 + g * 16][0]);
        gll16(Wb + (size_t)(n0 + wv * 16 + lrow) * 256 + kc + sgr,
              &Bs[buf][wv * 16][0]);
    };
    auto compute = [&](int buf) {
        bf16x8 a[4], b[2];
#pragma unroll
        for (int i = 0; i < 4; ++i)
            a[i] = *(const bf16x8*)&As[buf][wm * 64 + i * 16 + r][ax8];
#pragma unroll
        for (int j = 0; j < 2; ++j)
            b[j] = *(const bf16x8*)&Bs[buf][wn * 32 + j * 16 + r][ax8];
#pragma unroll
        for (int i = 0; i < 4; ++i)
#pragma unroll
            for (int j = 0; j < 2; ++j)
                acc[i][j] = __builtin_amdgcn_mfma_f32_16x16x32_bf16(b[j], a[i], acc[i][j], 0, 0, 0);
    };

    stage(0, 0);
    __syncthreads();
#pragma unroll
    for (int t = 0; t < 7; ++t) {
        const int cur = t & 1, nxt = cur ^ 1;
        stage((t + 1) * 32, nxt);
        compute(cur);
        __syncthreads();
    }
    compute(1);

#pragma unroll
    for (int i = 0; i < 4; ++i) {
        const int rowg = m0 + wm * 64 + i * 16 + r;
#pragma unroll
        for (int j = 0; j < 2; ++j) {
            const int nb = n0 + wn * 32 + j * 16 + q * 4;
            f32x4 bi = *(const f32x4*)(bias + nb);
            f32x4 o;
#pragma unroll
            for (int reg = 0; reg < 4; ++reg) o[reg] = acc[i][j][reg] + bi[reg];
            *(f32x4*)&Out[(size_t)rowg * 256 + nb] = o;
        }
    }
}

// Fused per-(window,head) linear attention on blocked QKV layout.
__global__ __launch_bounds__(256) void kvy_kernel(
    const bf16_t* __restrict__ QKV,   // [24][32768][32]
    const int* __restrict__ offsets,
    const int* __restrict__ counts,
    bf16_t* __restrict__ Y)           // [32768,256] row-major
{
    const int w = blockIdx.x;
    const int h = blockIdx.y;
    const int is64 = (counts[1] == 0) ? 1 : 0;
    const int off = offsets[w << is64];
    const int tid = threadIdx.x;
    const int lane = tid & 63;
    const int wv = tid >> 6;

    __shared__ __align__(16) bf16_t KT[32 * 264];   // KT[c][t]
    __shared__ __align__(16) bf16_t VT[32 * 264];   // VT[d][t]
    __shared__ __align__(16) bf16_t KVT[32 * 40];   // KVT[d][c]
    __shared__ float sbuf[32];
    __shared__ float spart[32 * 8];
    __shared__ float zinv[WIN];

    // P0: stage K,V transposed (thread = token); fully coalesced 64B/token reads
    {
        const int t = tid;
        const bf16_t* kp = QKV + ((size_t)(8 + h) * M_TOK + off + t) * 32;
        const bf16_t* vp = QKV + ((size_t)(16 + h) * M_TOK + off + t) * 32;
        bf16_t ka[32], va[32];
#pragma unroll
        for (int u = 0; u < 4; ++u) {
            bf16x8 kk = *(const bf16x8*)(kp + u * 8);
            bf16x8 vvv = *(const bf16x8*)(vp + u * 8);
#pragma unroll
            for (int j = 0; j < 8; ++j) { ka[u * 8 + j] = kk[j]; va[u * 8 + j] = vvv[j]; }
        }
#pragma unroll
        for (int c = 0; c < 32; ++c) {
            KT[c * 264 + t] = ka[c];
            VT[c * 264 + t] = va[c];
        }
    }
    __syncthreads();

    // P1a: s partials
    {
        const int c = tid >> 3;
        const int tc = (tid & 7) * 32;
        float ps = 0.f;
#pragma unroll
        for (int u = 0; u < 4; ++u) {
            bf16x8 kk = *(const bf16x8*)(&KT[c * 264 + tc + u * 8]);
#pragma unroll
            for (int j = 0; j < 8; ++j) ps += (float)kk[j];
        }
        spart[c * 8 + (tid & 7)] = ps;
    }
    // P1b: KV = K^T V via MFMA (col-field->d, row-field->c); store KVT[d][c]
    {
        const int i = wv >> 1, j = wv & 1;
        const int r = lane & 15, q = lane >> 4;
        f32x4 acc = {};
#pragma unroll
        for (int ch = 0; ch < 8; ++ch) {
            bf16x8 af = *(const bf16x8*)(&KT[(i * 16 + r) * 264 + ch * 32 + q * 8]);
            bf16x8 bf_ = *(const bf16x8*)(&VT[(j * 16 + r) * 264 + ch * 32 + q * 8]);
            acc = __builtin_amdgcn_mfma_f32_16x16x32_bf16(af, bf_, acc, 0, 0, 0);
        }
        bf16x4 kv4;
#pragma unroll
        for (int reg = 0; reg < 4; ++reg) kv4[reg] = (bf16_t)acc[reg];
        *(bf16x4*)(&KVT[(j * 16 + r) * 40 + i * 16 + q * 4]) = kv4;
    }
    __syncthreads();
    if (tid < 32) {
        float s = 0.f;
#pragma unroll
        for (int u = 0; u < 8; ++u) s += spart[tid * 8 + u];
        sbuf[tid] = s;
    }
    __syncthreads();

    // P2: zinv[t]
    {
        const int t = tid;
        const bf16_t* qp = QKV + ((size_t)h * M_TOK + off + t) * 32;
        float z = 0.f;
#pragma unroll
        for (int u = 0; u < 4; ++u) {
            bf16x8 qq = *(const bf16x8*)(qp + u * 8);
#pragma unroll
            for (int j = 0; j < 8; ++j) z += (float)qq[j] * sbuf[u * 8 + j];
        }
        zinv[t] = 1.0f / (z + 1e-3f);
    }
    __syncthreads();

    // P3: y = (Q.KV)*zinv via swapped MFMA (col-field->t, row-field->d): bf16x4 stores
    {
        const int r = lane & 15, q = lane >> 4;
        bf16x8 b0 = *(const bf16x8*)(&KVT[(r) * 40 + q * 8]);        // d=r   (j=0)
        bf16x8 b1 = *(const bf16x8*)(&KVT[(16 + r) * 40 + q * 8]);   // d=16+r(j=1)
#pragma unroll
        for (int u = 0; u < 4; ++u) {
            const int mi = wv * 4 + u;
            const bf16_t* ap = QKV + ((size_t)h * M_TOK + off + mi * 16 + r) * 32 + q * 8;
            bf16x8 af = *(const bf16x8*)ap;
            f32x4 acc0 = {}, acc1 = {};
            acc0 = __builtin_amdgcn_mfma_f32_16x16x32_bf16(b0, af, acc0, 0, 0, 0);
            acc1 = __builtin_amdgcn_mfma_f32_16x16x32_bf16(b1, af, acc1, 0, 0, 0);
            const int tkn = mi * 16 + r;
            const float zi = zinv[tkn];
            bf16_t* yp = Y + (size_t)(off + tkn) * 256 + h * 32;
            bf16x4 o0, o1;
#pragma unroll
            for (int reg = 0; reg < 4; ++reg) {
                o0[reg] = (bf16_t)(acc0[reg] * zi);
                o1[reg] = (bf16_t)(acc1[reg] * zi);
            }
            *(bf16x4*)(yp + q * 4) = o0;
            *(bf16x4*)(yp + 16 + q * 4) = o1;
        }
    }
}

extern "C" void kernel_launch(void* const* d_in, const int* in_sizes, int n_in,
                              void* d_out, int out_size, void* d_ws, size_t ws_size,
                              hipStream_t stream) {
    const float* x      = (const float*)d_in[0];
    const float* w_qkv  = (const float*)d_in[1];
    const float* w_proj = (const float*)d_in[2];
    const float* b_proj = (const float*)d_in[3];
    const int*   offs   = (const int*)d_in[4];
    const int*   cnts   = (const int*)d_in[5];

    char* ws = (char*)d_ws;
    bf16_t* QKV = (bf16_t*)ws;                    // 24*32768*32*2 = 50331648 B
    bf16_t* Y   = (bf16_t*)(ws + 50331648);       // 16777216 B
    bf16_t* Wqb = (bf16_t*)(ws + 67108864);       //   393216 B
    bf16_t* Wpb = (bf16_t*)(ws + 67502080);       //   131072 B
    float*  out = (float*)d_out;

    // 0) weights fp32 -> bf16 (0.5 MB)
    wconv<<<256, 256, 0, stream>>>(w_qkv, w_proj, Wqb, Wpb);

    // 1) QKV gemm (fp32 X converted in-kernel, blocked output layout)
    gemm1_qkv<<<1536, 256, 0, stream>>>(x, Wqb, QKV);

    // 2+3) fused per-(window,head) KV + normalize
    kvy_kernel<<<dim3(NWIN, 8), 256, 0, stream>>>(QKV, offs, cnts, Y);

    // 4) proj gemm, fp32 out
    gemm2_proj<<<1024, 256, 0, stream>>>(Y, Wpb, b_proj, out);
}

// Round 4
// 145.420 us; speedup vs baseline: 1.0259x; 1.0259x over previous
//
#include <hip/hip_runtime.h>

typedef __bf16 bf16_t;
typedef bf16_t bf16x8 __attribute__((ext_vector_type(8)));
typedef bf16_t bf16x4 __attribute__((ext_vector_type(4)));
typedef float f32x4 __attribute__((ext_vector_type(4)));

#define M_TOK 32768
#define NWIN 128
#define WIN  256

typedef __attribute__((address_space(3))) void* as3p;
typedef const __attribute__((address_space(1))) void* as1p;

__device__ __forceinline__ void gll16(const void* g, void* l) {
    __builtin_amdgcn_global_load_lds((as1p)g, (as3p)l, 16, 0, 0);
}

__device__ __forceinline__ bf16x8 cvt8(f32x4 a, f32x4 b) {
    bf16x8 o;
    o[0] = (bf16_t)a[0]; o[1] = (bf16_t)a[1]; o[2] = (bf16_t)a[2]; o[3] = (bf16_t)a[3];
    o[4] = (bf16_t)b[0]; o[5] = (bf16_t)b[1]; o[6] = (bf16_t)b[2]; o[7] = (bf16_t)b[3];
    return o;
}

// counted-vmcnt wait (T4): leave future prefetches in flight across barriers
#define VMW_(n) asm volatile("s_waitcnt vmcnt(" #n ")" ::: "memory")
#define VMW(n) VMW_(n)

// tiny fp32->bf16 weight convert (w_qkv 196608 + w_proj 65536 elems)
__global__ __launch_bounds__(256) void wconv(
    const float* __restrict__ wq, const float* __restrict__ wp,
    bf16_t* __restrict__ wqb, bf16_t* __restrict__ wpb)
{
    int i4 = (blockIdx.x * 256 + threadIdx.x) * 4;
    const float* s; bf16_t* dst; int idx;
    if (i4 < 196608) { s = wq; dst = wqb; idx = i4; }
    else             { s = wp; dst = wpb; idx = i4 - 196608; }
    f32x4 v = *(const f32x4*)(s + idx);
    bf16x4 o;
    o[0] = (bf16_t)v[0]; o[1] = (bf16_t)v[1]; o[2] = (bf16_t)v[2]; o[3] = (bf16_t)v[3];
    *(bf16x4*)(dst + idx) = o;
}

// GEMM1: QKV = relu_qk(X @ Wqkv^T). X fp32 [32768,256] staged fp32 via gll16,
// cvt at fragment read. Output QKV[nblk][tok][32], nblk=n>>5 (0..7 q, 8..15 k, 16..23 v).
// T3+T4: triple-buffered BK=32, counted vmcnt, raw s_barrier (prefetch survives barriers).
// vmcnt ledger: prologue=18 in flight; VMW(12) retires step-t (6 insts); tail 6/0.
// LDS swizzle: A (fp32, 128B rows, 8x16B granules) g^=row&7; B (bf16, 64B rows) g^=row&3.
__global__ __launch_bounds__(256) void gemm1_qkv(
    const float* __restrict__ X,
    const bf16_t* __restrict__ Wb,
    bf16_t* __restrict__ QKV)
{
    __shared__ __align__(16) float  As[3][128][32];   // 48KB
    __shared__ __align__(16) bf16_t Bs[3][128][32];   // 24KB

    const int tid = threadIdx.x;
    const int lane = tid & 63;
    const int wv = tid >> 6;
    const int wm = wv >> 1, wn = wv & 1;
    // supertile swizzle: 8 m-blocks x 6 n-blocks share A/B panels in L2
    const int id = blockIdx.x;
    const int sg = id / 48, wsub = id % 48;
    const int m0 = (sg * 8 + (wsub & 7)) * 128;
    const int n0 = (wsub >> 3) * 128;
    const int r = lane & 15, q = lane >> 4;
    // A staging: inst = 8 rows x 128B; lane -> row lane>>3, granule lane&7 (pre-swizzled src)
    const int arow = lane >> 3;
    const int ag = (lane & 7) ^ arow;            // arow in 0..7
    // B staging: inst = 16 rows x 64B; lane -> row lane>>2, granule lane&3
    const int brow = lane >> 2;
    const int bg = (lane & 3) ^ (brow & 3);

    f32x4 acc[4][4] = {};

    auto stage = [&](int t, int buf) {
        const int kc = t * 32;
#pragma unroll
        for (int u = 0; u < 4; ++u) {            // 4 A-insts/wave
            const int rb = wv * 32 + u * 8;
            gll16(X + (size_t)(m0 + rb + arow) * 256 + kc + ag * 4, &As[buf][rb][0]);
        }
#pragma unroll
        for (int u = 0; u < 2; ++u) {            // 2 B-insts/wave
            const int rb = wv * 32 + u * 16;
            gll16(Wb + (size_t)(n0 + rb + brow) * 256 + kc + bg * 8, &Bs[buf][rb][0]);
        }
    };
    auto compute = [&](int buf) {
        bf16x8 a[4], b[4];
#pragma unroll
        for (int i = 0; i < 4; ++i) {
            const int row = wm * 64 + i * 16 + r;
            const int g0 = (2 * q) ^ (r & 7);         // global granule 2q  (k=q*8..+3)
            const int g1 = (2 * q + 1) ^ (r & 7);     // global granule 2q+1(k=q*8+4..+7)
            f32x4 lo = *(const f32x4*)&As[buf][row][g0 * 4];
            f32x4 hi = *(const f32x4*)&As[buf][row][g1 * 4];
            a[i] = cvt8(lo, hi);
        }
#pragma unroll
        for (int j = 0; j < 4; ++j)
            b[j] = *(const bf16x8*)&Bs[buf][wn * 64 + j * 16 + r][(q ^ (r & 3)) * 8];
#pragma unroll
        for (int i = 0; i < 4; ++i)
#pragma unroll
            for (int j = 0; j < 4; ++j)   // swapped: col-field->m(r), row-field->n(q*4+reg)
                acc[i][j] = __builtin_amdgcn_mfma_f32_16x16x32_bf16(b[j], a[i], acc[i][j], 0, 0, 0);
    };

    // prologue: 3 steps in flight (18 gll16/wave)
    stage(0, 0); stage(1, 1); stage(2, 2);

#define G1_STEP(t, NW) do { \
        VMW(NW); \
        __builtin_amdgcn_s_barrier(); \
        __builtin_amdgcn_sched_barrier(0); \
        compute((t) % 3); \
        __builtin_amdgcn_sched_barrier(0); \
        __builtin_amdgcn_s_barrier(); \
        if ((t) + 3 < 8) stage((t) + 3, (t) % 3); \
    } while (0)

    G1_STEP(0, 12); G1_STEP(1, 12); G1_STEP(2, 12); G1_STEP(3, 12);
    G1_STEP(4, 12); G1_STEP(5, 12); G1_STEP(6, 6);  G1_STEP(7, 0);
#undef G1_STEP

#pragma unroll
    for (int i = 0; i < 4; ++i) {
        const int rowg = m0 + wm * 64 + i * 16 + r;
#pragma unroll
        for (int j = 0; j < 4; ++j) {
            const int nb = n0 + wn * 64 + j * 16 + q * 4;
            const int nblk = nb >> 5, d = nb & 31;
            bf16x4 o;
#pragma unroll
            for (int reg = 0; reg < 4; ++reg) {
                float v = acc[i][j][reg];
                if (nblk < 16) v = fmaxf(v, 0.0f);   // relu on q,k (n<512)
                o[reg] = (bf16_t)v;
            }
            *(bf16x4*)&QKV[((size_t)nblk * M_TOK + rowg) * 32 + d] = o;
        }
    }
}

// GEMM2: Out = Y @ Wproj^T + b, Y bf16 [32768,256], Out fp32. Tile 128x64.
// Same T3+T4 pipeline; 36KB LDS -> 4 blocks/CU; 3 gll16/wave/step -> vmcnt 6/3/0.
__global__ __launch_bounds__(256) void gemm2_proj(
    const bf16_t* __restrict__ Y,
    const bf16_t* __restrict__ Wb,
    const float* __restrict__ bias,
    float* __restrict__ Out)
{
    __shared__ __align__(16) bf16_t As[3][128][32];   // 24KB
    __shared__ __align__(16) bf16_t Bs[3][64][32];    // 12KB

    const int tid = threadIdx.x;
    const int lane = tid & 63;
    const int wv = tid >> 6;
    const int wm = wv >> 1, wn = wv & 1;
    const int id = blockIdx.x;
    const int sg = id / 32, wsub = id % 32;      // supertile: 8m x 4n
    const int m0 = (sg * 8 + (wsub & 7)) * 128;
    const int n0 = (wsub >> 3) * 64;
    const int r = lane & 15, q = lane >> 4;
    const int brow = lane >> 2;
    const int bg = (lane & 3) ^ (brow & 3);

    f32x4 acc[4][2] = {};

    auto stage = [&](int t, int buf) {
        const int kc = t * 32;
#pragma unroll
        for (int u = 0; u < 2; ++u) {            // 2 A-insts/wave (16 rows each)
            const int rb = wv * 32 + u * 16;
            gll16(Y + (size_t)(m0 + rb + brow) * 256 + kc + bg * 8, &As[buf][rb][0]);
        }
        gll16(Wb + (size_t)(n0 + wv * 16 + brow) * 256 + kc + bg * 8, &Bs[buf][wv * 16][0]);
    };
    auto compute = [&](int buf) {
        bf16x8 a[4], b[2];
#pragma unroll
        for (int i = 0; i < 4; ++i)
            a[i] = *(const bf16x8*)&As[buf][wm * 64 + i * 16 + r][(q ^ (r & 3)) * 8];
#pragma unroll
        for (int j = 0; j < 2; ++j)
            b[j] = *(const bf16x8*)&Bs[buf][wn * 32 + j * 16 + r][(q ^ (r & 3)) * 8];
#pragma unroll
        for (int i = 0; i < 4; ++i)
#pragma unroll
            for (int j = 0; j < 2; ++j)
                acc[i][j] = __builtin_amdgcn_mfma_f32_16x16x32_bf16(b[j], a[i], acc[i][j], 0, 0, 0);
    };

    stage(0, 0); stage(1, 1); stage(2, 2);

#define G2_STEP(t, NW) do { \
        VMW(NW); \
        __builtin_amdgcn_s_barrier(); \
        __builtin_amdgcn_sched_barrier(0); \
        compute((t) % 3); \
        __builtin_amdgcn_sched_barrier(0); \
        __builtin_amdgcn_s_barrier(); \
        if ((t) + 3 < 8) stage((t) + 3, (t) % 3); \
    } while (0)

    G2_STEP(0, 6); G2_STEP(1, 6); G2_STEP(2, 6); G2_STEP(3, 6);
    G2_STEP(4, 6); G2_STEP(5, 6); G2_STEP(6, 3); G2_STEP(7, 0);
#undef G2_STEP

#pragma unroll
    for (int i = 0; i < 4; ++i) {
        const int rowg = m0 + wm * 64 + i * 16 + r;
#pragma unroll
        for (int j = 0; j < 2; ++j) {
            const int nb = n0 + wn * 32 + j * 16 + q * 4;
            f32x4 bi = *(const f32x4*)(bias + nb);
            f32x4 o;
#pragma unroll
            for (int reg = 0; reg < 4; ++reg) o[reg] = acc[i][j][reg] + bi[reg];
            *(f32x4*)&Out[(size_t)rowg * 256 + nb] = o;
        }
    }
}

// Fused per-(window,head) linear attention on blocked QKV layout.
__global__ __launch_bounds__(256) void kvy_kernel(
    const bf16_t* __restrict__ QKV,   // [24][32768][32]
    const int* __restrict__ offsets,
    const int* __restrict__ counts,
    bf16_t* __restrict__ Y)           // [32768,256] row-major
{
    const int w = blockIdx.x;
    const int h = blockIdx.y;
    const int is64 = (counts[1] == 0) ? 1 : 0;
    const int off = offsets[w << is64];
    const int tid = threadIdx.x;
    const int lane = tid & 63;
    const int wv = tid >> 6;

    __shared__ __align__(16) bf16_t KT[32 * 264];   // KT[c][t]
    __shared__ __align__(16) bf16_t VT[32 * 264];   // VT[d][t]
    __shared__ __align__(16) bf16_t KVT[32 * 40];   // KVT[d][c]
    __shared__ float sbuf[32];
    __shared__ float spart[32 * 8];
    __shared__ float zinv[WIN];

    // P0: stage K,V transposed (thread = token); fully coalesced 64B/token reads
    {
        const int t = tid;
        const bf16_t* kp = QKV + ((size_t)(8 + h) * M_TOK + off + t) * 32;
        const bf16_t* vp = QKV + ((size_t)(16 + h) * M_TOK + off + t) * 32;
        bf16_t ka[32], va[32];
#pragma unroll
        for (int u = 0; u < 4; ++u) {
            bf16x8 kk = *(const bf16x8*)(kp + u * 8);
            bf16x8 vvv = *(const bf16x8*)(vp + u * 8);
#pragma unroll
            for (int j = 0; j < 8; ++j) { ka[u * 8 + j] = kk[j]; va[u * 8 + j] = vvv[j]; }
        }
#pragma unroll
        for (int c = 0; c < 32; ++c) {
            KT[c * 264 + t] = ka[c];
            VT[c * 264 + t] = va[c];
        }
    }
    __syncthreads();

    // P1a: s partials
    {
        const int c = tid >> 3;
        const int tc = (tid & 7) * 32;
        float ps = 0.f;
#pragma unroll
        for (int u = 0; u < 4; ++u) {
            bf16x8 kk = *(const bf16x8*)(&KT[c * 264 + tc + u * 8]);
#pragma unroll
            for (int j = 0; j < 8; ++j) ps += (float)kk[j];
        }
        spart[c * 8 + (tid & 7)] = ps;
    }
    // P1b: KV = K^T V via MFMA (col-field->d, row-field->c); store KVT[d][c]
    {
        const int i = wv >> 1, j = wv & 1;
        const int r = lane & 15, q = lane >> 4;
        f32x4 acc = {};
#pragma unroll
        for (int ch = 0; ch < 8; ++ch) {
            bf16x8 af = *(const bf16x8*)(&KT[(i * 16 + r) * 264 + ch * 32 + q * 8]);
            bf16x8 bf_ = *(const bf16x8*)(&VT[(j * 16 + r) * 264 + ch * 32 + q * 8]);
            acc = __builtin_amdgcn_mfma_f32_16x16x32_bf16(af, bf_, acc, 0, 0, 0);
        }
        bf16x4 kv4;
#pragma unroll
        for (int reg = 0; reg < 4; ++reg) kv4[reg] = (bf16_t)acc[reg];
        *(bf16x4*)(&KVT[(j * 16 + r) * 40 + i * 16 + q * 4]) = kv4;
    }
    __syncthreads();
    if (tid < 32) {
        float s = 0.f;
#pragma unroll
        for (int u = 0; u < 8; ++u) s += spart[tid * 8 + u];
        sbuf[tid] = s;
    }
    __syncthreads();

    // P2: zinv[t]
    {
        const int t = tid;
        const bf16_t* qp = QKV + ((size_t)h * M_TOK + off + t) * 32;
        float z = 0.f;
#pragma unroll
        for (int u = 0; u < 4; ++u) {
            bf16x8 qq = *(const bf16x8*)(qp + u * 8);
#pragma unroll
            for (int j = 0; j < 8; ++j) z += (float)qq[j] * sbuf[u * 8 + j];
        }
        zinv[t] = 1.0f / (z + 1e-3f);
    }
    __syncthreads();

    // P3: y = (Q.KV)*zinv via swapped MFMA (col-field->t, row-field->d): bf16x4 stores
    {
        const int r = lane & 15, q = lane >> 4;
        bf16x8 b0 = *(const bf16x8*)(&KVT[(r) * 40 + q * 8]);        // d=r   (j=0)
        bf16x8 b1 = *(const bf16x8*)(&KVT[(16 + r) * 40 + q * 8]);   // d=16+r(j=1)
#pragma unroll
        for (int u = 0; u < 4; ++u) {
            const int mi = wv * 4 + u;
            const bf16_t* ap = QKV + ((size_t)h * M_TOK + off + mi * 16 + r) * 32 + q * 8;
            bf16x8 af = *(const bf16x8*)ap;
            f32x4 acc0 = {}, acc1 = {};
            acc0 = __builtin_amdgcn_mfma_f32_16x16x32_bf16(b0, af, acc0, 0, 0, 0);
            acc1 = __builtin_amdgcn_mfma_f32_16x16x32_bf16(b1, af, acc1, 0, 0, 0);
            const int tkn = mi * 16 + r;
            const float zi = zinv[tkn];
            bf16_t* yp = Y + (size_t)(off + tkn) * 256 + h * 32;
            bf16x4 o0, o1;
#pragma unroll
            for (int reg = 0; reg < 4; ++reg) {
                o0[reg] = (bf16_t)(acc0[reg] * zi);
                o1[reg] = (bf16_t)(acc1[reg] * zi);
            }
            *(bf16x4*)(yp + q * 4) = o0;
            *(bf16x4*)(yp + 16 + q * 4) = o1;
        }
    }
}

extern "C" void kernel_launch(void* const* d_in, const int* in_sizes, int n_in,
                              void* d_out, int out_size, void* d_ws, size_t ws_size,
                              hipStream_t stream) {
    const float* x      = (const float*)d_in[0];
    const float* w_qkv  = (const float*)d_in[1];
    const float* w_proj = (const float*)d_in[2];
    const float* b_proj = (const float*)d_in[3];
    const int*   offs   = (const int*)d_in[4];
    const int*   cnts   = (const int*)d_in[5];

    char* ws = (char*)d_ws;
    bf16_t* QKV = (bf16_t*)ws;                    // 24*32768*32*2 = 50331648 B
    bf16_t* Y   = (bf16_t*)(ws + 50331648);       // 16777216 B
    bf16_t* Wqb = (bf16_t*)(ws + 67108864);       //   393216 B
    bf16_t* Wpb = (bf16_t*)(ws + 67502080);       //   131072 B
    float*  out = (float*)d_out;

    // 0) weights fp32 -> bf16 (0.5 MB)
    wconv<<<256, 256, 0, stream>>>(w_qkv, w_proj, Wqb, Wpb);

    // 1) QKV gemm (fp32 X staged via gll16, blocked output layout)
    gemm1_qkv<<<1536, 256, 0, stream>>>(x, Wqb, QKV);

    // 2+3) fused per-(window,head) KV + normalize
    kvy_kernel<<<dim3(NWIN, 8), 256, 0, stream>>>(QKV, offs, cnts, Y);

    // 4) proj gemm, fp32 out
    gemm2_proj<<<1024, 256, 0, stream>>>(Y, Wpb, b_proj, out);
}

// Round 5
// 141.581 us; speedup vs baseline: 1.0537x; 1.0271x over previous
//
#include <hip/hip_runtime.h>

typedef __bf16 bf16_t;
typedef bf16_t bf16x8 __attribute__((ext_vector_type(8)));
typedef bf16_t bf16x4 __attribute__((ext_vector_type(4)));
typedef float f32x4 __attribute__((ext_vector_type(4)));

#define M_TOK 32768
#define NWIN 128
#define WIN  256

typedef __attribute__((address_space(3))) void* as3p;
typedef const __attribute__((address_space(1))) void* as1p;

__device__ __forceinline__ void gll16(const void* g, void* l) {
    __builtin_amdgcn_global_load_lds((as1p)g, (as3p)l, 16, 0, 0);
}

__device__ __forceinline__ bf16x8 cvt8(f32x4 a, f32x4 b) {
    bf16x8 o;
    o[0] = (bf16_t)a[0]; o[1] = (bf16_t)a[1]; o[2] = (bf16_t)a[2]; o[3] = (bf16_t)a[3];
    o[4] = (bf16_t)b[0]; o[5] = (bf16_t)b[1]; o[6] = (bf16_t)b[2]; o[7] = (bf16_t)b[3];
    return o;
}

// counted-vmcnt wait (T4): leave future prefetches in flight across barriers
#define VMW_(n) asm volatile("s_waitcnt vmcnt(" #n ")" ::: "memory")
#define VMW(n) VMW_(n)

// tiny fp32->bf16 weight convert (w_qkv 196608 + w_proj 65536 elems)
__global__ __launch_bounds__(256) void wconv(
    const float* __restrict__ wq, const float* __restrict__ wp,
    bf16_t* __restrict__ wqb, bf16_t* __restrict__ wpb)
{
    int i4 = (blockIdx.x * 256 + threadIdx.x) * 4;
    const float* s; bf16_t* dst; int idx;
    if (i4 < 196608) { s = wq; dst = wqb; idx = i4; }
    else             { s = wp; dst = wpb; idx = i4 - 196608; }
    f32x4 v = *(const f32x4*)(s + idx);
    bf16x4 o;
    o[0] = (bf16_t)v[0]; o[1] = (bf16_t)v[1]; o[2] = (bf16_t)v[2]; o[3] = (bf16_t)v[3];
    *(bf16x4*)(dst + idx) = o;
}

// GEMM1: QKV = relu_qk(X @ Wqkv^T). One block per 128-row panel (256 blocks x 512 thr).
// X panel converted fp32->bf16 ONCE into persistent LDS (64KB, granule^row&7 swizzle);
// loop 6 n-blocks x 4 K-steps (BK=64), B triple-buffered via gll16 + counted vmcnt.
// Traffic: X read once (33.5MB total), B from per-XCD L2 (393KB), QKV write 48MB.
__global__ __launch_bounds__(512) void gemm1_qkv(
    const float* __restrict__ X,
    const bf16_t* __restrict__ Wb,
    bf16_t* __restrict__ QKV)
{
    __shared__ __align__(16) bf16_t Al[128][256];     // 64KB persistent A panel
    __shared__ __align__(16) bf16_t Bs[3][128][64];   // 48KB B triple buffer

    const int tid = threadIdx.x;
    const int lane = tid & 63;
    const int wv = tid >> 6;                 // 0..7
    const int wm = wv >> 2, wn = wv & 3;     // wave tile 64m x 32n
    const int m0 = blockIdx.x * 128;
    const int r = lane & 15, q = lane >> 4;
    const int rl = lane >> 3, gsl = lane & 7;   // B-stage: 8 rows x 128B per inst

    f32x4 acc[4][2] = {};

    // B stage: 2 gll16/wave/step; LDS slot granule gs holds global granule gs^(row&7)
    auto stageB = [&](int t) {
        const int nb = t >> 2, kc = (t & 3) * 64;
#pragma unroll
        for (int u = 0; u < 2; ++u)
            gll16(Wb + (size_t)(nb * 128 + wv * 16 + u * 8 + rl) * 256 + kc + (gsl ^ rl) * 8,
                  &Bs[t % 3][wv * 16 + u * 8][0]);
    };

    auto comp = [&](int t) {
        const int buf = t % 3;
#pragma unroll
        for (int s = 0; s < 2; ++s) {
            const int kk = (t & 3) * 2 + s;   // 32-wide k-chunk index (0..7)
            bf16x8 a[4], b[2];
#pragma unroll
            for (int i = 0; i < 4; ++i)
                a[i] = *(const bf16x8*)((const bf16_t*)Al +
                        (wm * 64 + i * 16 + r) * 256 + ((kk * 4 + q) ^ (r & 7)) * 8);
#pragma unroll
            for (int j = 0; j < 2; ++j)
                b[j] = *(const bf16x8*)&Bs[buf][wn * 32 + j * 16 + r][((s * 4 + q) ^ (r & 7)) * 8];
#pragma unroll
            for (int i = 0; i < 4; ++i)
#pragma unroll
                for (int j = 0; j < 2; ++j)   // swapped: col-field->m(r), row-field->n(q*4+reg)
                    acc[i][j] = __builtin_amdgcn_mfma_f32_16x16x32_bf16(b[j], a[i], acc[i][j], 0, 0, 0);
        }
    };

    auto wout = [&](int nb) {
#pragma unroll
        for (int i = 0; i < 4; ++i) {
            const int rowg = m0 + wm * 64 + i * 16 + r;
#pragma unroll
            for (int j = 0; j < 2; ++j) {
                const int nbcol = nb * 128 + wn * 32 + j * 16 + q * 4;
                const int nblk = nbcol >> 5, d = nbcol & 31;
                bf16x4 o;
#pragma unroll
                for (int reg = 0; reg < 4; ++reg) {
                    float v = acc[i][j][reg];
                    if (nblk < 16) v = fmaxf(v, 0.0f);   // relu on q,k (n<512)
                    o[reg] = (bf16_t)v;
                }
                *(bf16x4*)&QKV[((size_t)nblk * M_TOK + rowg) * 32 + d] = o;
                acc[i][j] = (f32x4){0.f, 0.f, 0.f, 0.f};
            }
        }
    };

    // prologue: first 3 B-steps in flight (their latency hides under conversion)
    stageB(0); stageB(1); stageB(2);

    // A conversion: X fp32 -> bf16 swizzled into Al (131KB read, once)
#pragma unroll
    for (int it = 0; it < 16; ++it) {
        const int L = it * 512 + tid;             // f32x4 index in [0,8192)
        const int row = L >> 6, col4 = L & 63;
        f32x4 v = *(const f32x4*)(X + (size_t)(m0 + row) * 256 + col4 * 4);
        bf16x4 o;
        o[0] = (bf16_t)v[0]; o[1] = (bf16_t)v[1]; o[2] = (bf16_t)v[2]; o[3] = (bf16_t)v[3];
        const int gs = (col4 >> 1) ^ (row & 7);   // granule swizzle
        *(bf16x4*)((bf16_t*)Al + row * 256 + gs * 8 + (col4 & 1) * 4) = o;
    }
    __syncthreads();   // drains conversion loads+writes and B steps 0-2

#define G1S(t, NW) do { \
        VMW(NW); \
        __builtin_amdgcn_s_barrier(); \
        __builtin_amdgcn_sched_barrier(0); \
        comp(t); \
        if (((t) & 3) == 3) wout((t) >> 2); \
        __builtin_amdgcn_sched_barrier(0); \
        __builtin_amdgcn_s_barrier(); \
        if ((t) + 3 < 24) stageB((t) + 3); \
    } while (0)

    G1S(0, 4);  G1S(1, 4);  G1S(2, 4);  G1S(3, 4);
    G1S(4, 4);  G1S(5, 4);  G1S(6, 4);  G1S(7, 4);
    G1S(8, 4);  G1S(9, 4);  G1S(10, 4); G1S(11, 4);
    G1S(12, 4); G1S(13, 4); G1S(14, 4); G1S(15, 4);
    G1S(16, 4); G1S(17, 4); G1S(18, 4); G1S(19, 4);
    G1S(20, 4); G1S(21, 4); G1S(22, 2); G1S(23, 0);
#undef G1S
}

// GEMM2: Out = Y @ Wproj^T + b. Same panel structure: Y panel (bf16) staged ONCE
// via gll16 with pre-swizzled source; 2 n-blocks x 4 K-steps (BK=64).
__global__ __launch_bounds__(512) void gemm2_proj(
    const bf16_t* __restrict__ Y,
    const bf16_t* __restrict__ Wb,
    const float* __restrict__ bias,
    float* __restrict__ Out)
{
    __shared__ __align__(16) bf16_t Al[128][256];     // 64KB persistent A panel
    __shared__ __align__(16) bf16_t Bs[3][128][64];   // 48KB B triple buffer

    const int tid = threadIdx.x;
    const int lane = tid & 63;
    const int wv = tid >> 6;
    const int wm = wv >> 2, wn = wv & 3;
    const int m0 = blockIdx.x * 128;
    const int r = lane & 15, q = lane >> 4;
    const int rl = lane >> 3, gsl = lane & 7;

    f32x4 acc[4][2] = {};

    auto stageB = [&](int t) {
        const int nb = t >> 2, kc = (t & 3) * 64;
#pragma unroll
        for (int u = 0; u < 2; ++u)
            gll16(Wb + (size_t)(nb * 128 + wv * 16 + u * 8 + rl) * 256 + kc + (gsl ^ rl) * 8,
                  &Bs[t % 3][wv * 16 + u * 8][0]);
    };

    auto comp = [&](int t) {
        const int buf = t % 3;
#pragma unroll
        for (int s = 0; s < 2; ++s) {
            const int kk = (t & 3) * 2 + s;
            bf16x8 a[4], b[2];
#pragma unroll
            for (int i = 0; i < 4; ++i)
                a[i] = *(const bf16x8*)((const bf16_t*)Al +
                        (wm * 64 + i * 16 + r) * 256 + ((kk * 4 + q) ^ (r & 7)) * 8);
#pragma unroll
            for (int j = 0; j < 2; ++j)
                b[j] = *(const bf16x8*)&Bs[buf][wn * 32 + j * 16 + r][((s * 4 + q) ^ (r & 7)) * 8];
#pragma unroll
            for (int i = 0; i < 4; ++i)
#pragma unroll
                for (int j = 0; j < 2; ++j)
                    acc[i][j] = __builtin_amdgcn_mfma_f32_16x16x32_bf16(b[j], a[i], acc[i][j], 0, 0, 0);
        }
    };

    auto wout = [&](int nb) {
#pragma unroll
        for (int i = 0; i < 4; ++i) {
            const int rowg = m0 + wm * 64 + i * 16 + r;
#pragma unroll
            for (int j = 0; j < 2; ++j) {
                const int n = nb * 128 + wn * 32 + j * 16 + q * 4;
                f32x4 bi = *(const f32x4*)(bias + n);
                f32x4 o;
#pragma unroll
                for (int reg = 0; reg < 4; ++reg) o[reg] = acc[i][j][reg] + bi[reg];
                *(f32x4*)&Out[(size_t)rowg * 256 + n] = o;
                acc[i][j] = (f32x4){0.f, 0.f, 0.f, 0.f};
            }
        }
    };

    // A panel staged once: 8 gll16/wave; inst covers 2 rows; src pre-swizzled per lane
    {
#pragma unroll
        for (int u = 0; u < 8; ++u) {
            const int rowl = wv * 16 + u * 2 + (lane >> 5);
            const int gsrc = (lane & 31) ^ (rowl & 7);
            gll16(Y + (size_t)(m0 + rowl) * 256 + gsrc * 8, &Al[wv * 16 + u * 2][0]);
        }
    }
    stageB(0); stageB(1); stageB(2);   // 6 more insts; total 14 in flight

#define G2S(t, NW) do { \
        VMW(NW); \
        __builtin_amdgcn_s_barrier(); \
        __builtin_amdgcn_sched_barrier(0); \
        comp(t); \
        if (((t) & 3) == 3) wout((t) >> 2); \
        __builtin_amdgcn_sched_barrier(0); \
        __builtin_amdgcn_s_barrier(); \
        if ((t) + 3 < 8) stageB((t) + 3); \
    } while (0)

    // t=0: VMW(4) retires A(8) + B0(2), leaves B1,B2
    G2S(0, 4); G2S(1, 4); G2S(2, 4); G2S(3, 4);
    G2S(4, 4); G2S(5, 4); G2S(6, 2); G2S(7, 0);
#undef G2S
}

// Fused per-(window,head) linear attention on blocked QKV layout.
__global__ __launch_bounds__(256) void kvy_kernel(
    const bf16_t* __restrict__ QKV,   // [24][32768][32]
    const int* __restrict__ offsets,
    const int* __restrict__ counts,
    bf16_t* __restrict__ Y)           // [32768,256] row-major
{
    const int w = blockIdx.x;
    const int h = blockIdx.y;
    const int is64 = (counts[1] == 0) ? 1 : 0;
    const int off = offsets[w << is64];
    const int tid = threadIdx.x;
    const int lane = tid & 63;
    const int wv = tid >> 6;

    __shared__ __align__(16) bf16_t KT[32 * 264];   // KT[c][t]
    __shared__ __align__(16) bf16_t VT[32 * 264];   // VT[d][t]
    __shared__ __align__(16) bf16_t KVT[32 * 40];   // KVT[d][c]
    __shared__ float sbuf[32];
    __shared__ float spart[32 * 8];
    __shared__ float zinv[WIN];

    // P0: stage K,V transposed (thread = token); fully coalesced 64B/token reads
    {
        const int t = tid;
        const bf16_t* kp = QKV + ((size_t)(8 + h) * M_TOK + off + t) * 32;
        const bf16_t* vp = QKV + ((size_t)(16 + h) * M_TOK + off + t) * 32;
        bf16_t ka[32], va[32];
#pragma unroll
        for (int u = 0; u < 4; ++u) {
            bf16x8 kk = *(const bf16x8*)(kp + u * 8);
            bf16x8 vvv = *(const bf16x8*)(vp + u * 8);
#pragma unroll
            for (int j = 0; j < 8; ++j) { ka[u * 8 + j] = kk[j]; va[u * 8 + j] = vvv[j]; }
        }
#pragma unroll
        for (int c = 0; c < 32; ++c) {
            KT[c * 264 + t] = ka[c];
            VT[c * 264 + t] = va[c];
        }
    }
    __syncthreads();

    // P1a: s partials
    {
        const int c = tid >> 3;
        const int tc = (tid & 7) * 32;
        float ps = 0.f;
#pragma unroll
        for (int u = 0; u < 4; ++u) {
            bf16x8 kk = *(const bf16x8*)(&KT[c * 264 + tc + u * 8]);
#pragma unroll
            for (int j = 0; j < 8; ++j) ps += (float)kk[j];
        }
        spart[c * 8 + (tid & 7)] = ps;
    }
    // P1b: KV = K^T V via MFMA (col-field->d, row-field->c); store KVT[d][c]
    {
        const int i = wv >> 1, j = wv & 1;
        const int r = lane & 15, q = lane >> 4;
        f32x4 acc = {};
#pragma unroll
        for (int ch = 0; ch < 8; ++ch) {
            bf16x8 af = *(const bf16x8*)(&KT[(i * 16 + r) * 264 + ch * 32 + q * 8]);
            bf16x8 bf_ = *(const bf16x8*)(&VT[(j * 16 + r) * 264 + ch * 32 + q * 8]);
            acc = __builtin_amdgcn_mfma_f32_16x16x32_bf16(af, bf_, acc, 0, 0, 0);
        }
        bf16x4 kv4;
#pragma unroll
        for (int reg = 0; reg < 4; ++reg) kv4[reg] = (bf16_t)acc[reg];
        *(bf16x4*)(&KVT[(j * 16 + r) * 40 + i * 16 + q * 4]) = kv4;
    }
    __syncthreads();
    if (tid < 32) {
        float s = 0.f;
#pragma unroll
        for (int u = 0; u < 8; ++u) s += spart[tid * 8 + u];
        sbuf[tid] = s;
    }
    __syncthreads();

    // P2: zinv[t]
    {
        const int t = tid;
        const bf16_t* qp = QKV + ((size_t)h * M_TOK + off + t) * 32;
        float z = 0.f;
#pragma unroll
        for (int u = 0; u < 4; ++u) {
            bf16x8 qq = *(const bf16x8*)(qp + u * 8);
#pragma unroll
            for (int j = 0; j < 8; ++j) z += (float)qq[j] * sbuf[u * 8 + j];
        }
        zinv[t] = 1.0f / (z + 1e-3f);
    }
    __syncthreads();

    // P3: y = (Q.KV)*zinv via swapped MFMA (col-field->t, row-field->d): bf16x4 stores
    {
        const int r = lane & 15, q = lane >> 4;
        bf16x8 b0 = *(const bf16x8*)(&KVT[(r) * 40 + q * 8]);        // d=r   (j=0)
        bf16x8 b1 = *(const bf16x8*)(&KVT[(16 + r) * 40 + q * 8]);   // d=16+r(j=1)
#pragma unroll
        for (int u = 0; u < 4; ++u) {
            const int mi = wv * 4 + u;
            const bf16_t* ap = QKV + ((size_t)h * M_TOK + off + mi * 16 + r) * 32 + q * 8;
            bf16x8 af = *(const bf16x8*)ap;
            f32x4 acc0 = {}, acc1 = {};
            acc0 = __builtin_amdgcn_mfma_f32_16x16x32_bf16(b0, af, acc0, 0, 0, 0);
            acc1 = __builtin_amdgcn_mfma_f32_16x16x32_bf16(b1, af, acc1, 0, 0, 0);
            const int tkn = mi * 16 + r;
            const float zi = zinv[tkn];
            bf16_t* yp = Y + (size_t)(off + tkn) * 256 + h * 32;
            bf16x4 o0, o1;
#pragma unroll
            for (int reg = 0; reg < 4; ++reg) {
                o0[reg] = (bf16_t)(acc0[reg] * zi);
                o1[reg] = (bf16_t)(acc1[reg] * zi);
            }
            *(bf16x4*)(yp + q * 4) = o0;
            *(bf16x4*)(yp + 16 + q * 4) = o1;
        }
    }
}

extern "C" void kernel_launch(void* const* d_in, const int* in_sizes, int n_in,
                              void* d_out, int out_size, void* d_ws, size_t ws_size,
                              hipStream_t stream) {
    const float* x      = (const float*)d_in[0];
    const float* w_qkv  = (const float*)d_in[1];
    const float* w_proj = (const float*)d_in[2];
    const float* b_proj = (const float*)d_in[3];
    const int*   offs   = (const int*)d_in[4];
    const int*   cnts   = (const int*)d_in[5];

    char* ws = (char*)d_ws;
    bf16_t* QKV = (bf16_t*)ws;                    // 24*32768*32*2 = 50331648 B
    bf16_t* Y   = (bf16_t*)(ws + 50331648);       // 16777216 B
    bf16_t* Wqb = (bf16_t*)(ws + 67108864);       //   393216 B
    bf16_t* Wpb = (bf16_t*)(ws + 67502080);       //   131072 B
    float*  out = (float*)d_out;

    // 0) weights fp32 -> bf16 (0.5 MB)
    wconv<<<256, 256, 0, stream>>>(w_qkv, w_proj, Wqb, Wpb);

    // 1) QKV gemm: one block per 128-row panel, X read once
    gemm1_qkv<<<256, 512, 0, stream>>>(x, Wqb, QKV);

    // 2+3) fused per-(window,head) KV + normalize
    kvy_kernel<<<dim3(NWIN, 8), 256, 0, stream>>>(QKV, offs, cnts, Y);

    // 4) proj gemm: one block per 128-row panel, Y read once
    gemm2_proj<<<256, 512, 0, stream>>>(Y, Wpb, b_proj, out);
}

// Round 7
// 138.108 us; speedup vs baseline: 1.0802x; 1.0251x over previous
//
#include <hip/hip_runtime.h>

typedef __bf16 bf16_t;
typedef bf16_t bf16x8 __attribute__((ext_vector_type(8)));
typedef bf16_t bf16x4 __attribute__((ext_vector_type(4)));
typedef float f32x4 __attribute__((ext_vector_type(4)));

#define M_TOK 32768
#define NWIN 128
#define WIN  256

typedef __attribute__((address_space(3))) void* as3p;
typedef const __attribute__((address_space(1))) void* as1p;

__device__ __forceinline__ void gll16(const void* g, void* l) {
    __builtin_amdgcn_global_load_lds((as1p)g, (as3p)l, 16, 0, 0);
}

// counted-vmcnt wait (T4): leave future prefetches in flight across barriers
#define VMW_(n) asm volatile("s_waitcnt vmcnt(" #n ")" ::: "memory")
#define VMW(n) VMW_(n)

// tiny fp32->bf16 weight convert (w_qkv 196608 + w_proj 65536 elems)
__global__ __launch_bounds__(256) void wconv(
    const float* __restrict__ wq, const float* __restrict__ wp,
    bf16_t* __restrict__ wqb, bf16_t* __restrict__ wpb)
{
    int i4 = (blockIdx.x * 256 + threadIdx.x) * 4;
    const float* s; bf16_t* dst; int idx;
    if (i4 < 196608) { s = wq; dst = wqb; idx = i4; }
    else             { s = wp; dst = wpb; idx = i4 - 196608; }
    f32x4 v = *(const f32x4*)(s + idx);
    bf16x4 o;
    o[0] = (bf16_t)v[0]; o[1] = (bf16_t)v[1]; o[2] = (bf16_t)v[2]; o[3] = (bf16_t)v[3];
    *(bf16x4*)(dst + idx) = o;
}

// GEMM1: QKV = relu_qk(X @ Wqkv^T). 512 blocks x 512 thr, 64-row panel each,
// 80KB LDS -> 2 blocks/CU (panel staging of block b+1 overlaps compute of block b).
// X panel converted fp32->bf16 ONCE into LDS (swizzle: slot s holds granule s^(row&7));
// 6 n-blocks x 4 K-steps (BK=64), B triple-buffered gll16 + counted vmcnt.
__global__ __launch_bounds__(512) void gemm1_qkv(
    const float* __restrict__ X,
    const bf16_t* __restrict__ Wb,
    bf16_t* __restrict__ QKV)
{
    __shared__ __align__(16) bf16_t Al[64][256];      // 32KB persistent A panel
    __shared__ __align__(16) bf16_t Bs[3][128][64];   // 48KB B triple buffer

    const int tid = threadIdx.x;
    const int lane = tid & 63;
    const int wv = tid >> 6;                 // 0..7
    const int wm = wv >> 2, wn = wv & 3;     // wave tile 32m x 32n
    const int m0 = blockIdx.x * 64;
    const int r = lane & 15, q = lane >> 4;
    const int rl = lane >> 3, gsl = lane & 7;   // B-stage: 8 rows x 128B per inst

    f32x4 acc[2][2] = {};

    // B stage: 2 gll16/wave/step; LDS slot granule s holds global granule s^(row&7)
    auto stageB = [&](int t) {
        const int nb = t >> 2, kc = (t & 3) * 64;
#pragma unroll
        for (int u = 0; u < 2; ++u)
            gll16(Wb + (size_t)(nb * 128 + wv * 16 + u * 8 + rl) * 256 + kc + (gsl ^ rl) * 8,
                  &Bs[t % 3][wv * 16 + u * 8][0]);
    };

    auto comp = [&](int t) {
        const int buf = t % 3;
#pragma unroll
        for (int s = 0; s < 2; ++s) {
            const int kk = (t & 3) * 2 + s;   // 32-wide k-chunk index (0..7)
            bf16x8 a[2], b[2];
#pragma unroll
            for (int i = 0; i < 2; ++i)
                a[i] = *(const bf16x8*)((const bf16_t*)Al +
                        (wm * 32 + i * 16 + r) * 256 + ((kk * 4 + q) ^ (r & 7)) * 8);
#pragma unroll
            for (int j = 0; j < 2; ++j)
                b[j] = *(const bf16x8*)&Bs[buf][wn * 32 + j * 16 + r][((s * 4 + q) ^ (r & 7)) * 8];
#pragma unroll
            for (int i = 0; i < 2; ++i)
#pragma unroll
                for (int j = 0; j < 2; ++j)   // swapped: col-field->m(r), row-field->n(q*4+reg)
                    acc[i][j] = __builtin_amdgcn_mfma_f32_16x16x32_bf16(b[j], a[i], acc[i][j], 0, 0, 0);
        }
    };

    auto wout = [&](int nb) {
#pragma unroll
        for (int i = 0; i < 2; ++i) {
            const int rowg = m0 + wm * 32 + i * 16 + r;
#pragma unroll
            for (int j = 0; j < 2; ++j) {
                const int nbcol = nb * 128 + wn * 32 + j * 16 + q * 4;
                const int nblk = nbcol >> 5, d = nbcol & 31;
                bf16x4 o;
#pragma unroll
                for (int reg = 0; reg < 4; ++reg) {
                    float v = acc[i][j][reg];
                    if (nblk < 16) v = fmaxf(v, 0.0f);   // relu on q,k (n<512)
                    o[reg] = (bf16_t)v;
                }
                *(bf16x4*)&QKV[((size_t)nblk * M_TOK + rowg) * 32 + d] = o;
                acc[i][j] = (f32x4){0.f, 0.f, 0.f, 0.f};
            }
        }
    };

    // A loads issued FIRST (so cvt's compiler wait is vmcnt(6), keeping B in flight)
    f32x4 av[8];
#pragma unroll
    for (int it = 0; it < 8; ++it) {
        const int L = it * 512 + tid;             // f32x4 index in [0,4096)
        const int row = L >> 6, col4 = L & 63;
        av[it] = *(const f32x4*)(X + (size_t)(m0 + row) * 256 + col4 * 4);
    }
    __builtin_amdgcn_sched_barrier(0);
    stageB(0); stageB(1); stageB(2);              // 6 gll16 in flight
    __builtin_amdgcn_sched_barrier(0);
#pragma unroll
    for (int it = 0; it < 8; ++it) {
        const int L = it * 512 + tid;
        const int row = L >> 6, col4 = L & 63;
        bf16x4 o;
        o[0] = (bf16_t)av[it][0]; o[1] = (bf16_t)av[it][1];
        o[2] = (bf16_t)av[it][2]; o[3] = (bf16_t)av[it][3];
        const int gs = (col4 >> 1) ^ (row & 7);   // granule swizzle
        *(bf16x4*)((bf16_t*)Al + row * 256 + gs * 8 + (col4 & 1) * 4) = o;
    }
    // publish A panel WITHOUT draining B prefetch (lgkm only, raw barrier)
    asm volatile("s_waitcnt lgkmcnt(0)" ::: "memory");
    __builtin_amdgcn_s_barrier();

#define G1S(t, NW) do { \
        VMW(NW); \
        __builtin_amdgcn_s_barrier(); \
        __builtin_amdgcn_sched_barrier(0); \
        comp(t); \
        if (((t) & 3) == 3) wout((t) >> 2); \
        __builtin_amdgcn_sched_barrier(0); \
        __builtin_amdgcn_s_barrier(); \
        if ((t) + 3 < 24) stageB((t) + 3); \
    } while (0)

    G1S(0, 4);  G1S(1, 4);  G1S(2, 4);  G1S(3, 4);
    G1S(4, 4);  G1S(5, 4);  G1S(6, 4);  G1S(7, 4);
    G1S(8, 4);  G1S(9, 4);  G1S(10, 4); G1S(11, 4);
    G1S(12, 4); G1S(13, 4); G1S(14, 4); G1S(15, 4);
    G1S(16, 4); G1S(17, 4); G1S(18, 4); G1S(19, 4);
    G1S(20, 4); G1S(21, 4); G1S(22, 2); G1S(23, 0);
#undef G1S
}

// GEMM2: Out = Y @ Wproj^T + b. 512 blocks x 512 thr, 64-row panel, 80KB LDS,
// 2 blocks/CU. Y panel (bf16) staged ONCE via gll16 pre-swizzled src;
// 2 n-blocks x 4 K-steps (BK=64).
__global__ __launch_bounds__(512) void gemm2_proj(
    const bf16_t* __restrict__ Y,
    const bf16_t* __restrict__ Wb,
    const float* __restrict__ bias,
    float* __restrict__ Out)
{
    __shared__ __align__(16) bf16_t Al[64][256];      // 32KB persistent A panel
    __shared__ __align__(16) bf16_t Bs[3][128][64];   // 48KB B triple buffer

    const int tid = threadIdx.x;
    const int lane = tid & 63;
    const int wv = tid >> 6;
    const int wm = wv >> 2, wn = wv & 3;
    const int m0 = blockIdx.x * 64;
    const int r = lane & 15, q = lane >> 4;
    const int rl = lane >> 3, gsl = lane & 7;

    f32x4 acc[2][2] = {};

    auto stageB = [&](int t) {
        const int nb = t >> 2, kc = (t & 3) * 64;
#pragma unroll
        for (int u = 0; u < 2; ++u)
            gll16(Wb + (size_t)(nb * 128 + wv * 16 + u * 8 + rl) * 256 + kc + (gsl ^ rl) * 8,
                  &Bs[t % 3][wv * 16 + u * 8][0]);
    };

    auto comp = [&](int t) {
        const int buf = t % 3;
#pragma unroll
        for (int s = 0; s < 2; ++s) {
            const int kk = (t & 3) * 2 + s;
            bf16x8 a[2], b[2];
#pragma unroll
            for (int i = 0; i < 2; ++i)
                a[i] = *(const bf16x8*)((const bf16_t*)Al +
                        (wm * 32 + i * 16 + r) * 256 + ((kk * 4 + q) ^ (r & 7)) * 8);
#pragma unroll
            for (int j = 0; j < 2; ++j)
                b[j] = *(const bf16x8*)&Bs[buf][wn * 32 + j * 16 + r][((s * 4 + q) ^ (r & 7)) * 8];
#pragma unroll
            for (int i = 0; i < 2; ++i)
#pragma unroll
                for (int j = 0; j < 2; ++j)
                    acc[i][j] = __builtin_amdgcn_mfma_f32_16x16x32_bf16(b[j], a[i], acc[i][j], 0, 0, 0);
        }
    };

    auto wout = [&](int nb) {
#pragma unroll
        for (int i = 0; i < 2; ++i) {
            const int rowg = m0 + wm * 32 + i * 16 + r;
#pragma unroll
            for (int j = 0; j < 2; ++j) {
                const int n = nb * 128 + wn * 32 + j * 16 + q * 4;
                f32x4 bi = *(const f32x4*)(bias + n);
                f32x4 o;
#pragma unroll
                for (int reg = 0; reg < 4; ++reg) o[reg] = acc[i][j][reg] + bi[reg];
                *(f32x4*)&Out[(size_t)rowg * 256 + n] = o;
                acc[i][j] = (f32x4){0.f, 0.f, 0.f, 0.f};
            }
        }
    };

    // A panel staged once: 4 gll16/wave (1 inst = 2 rows of 512B); src pre-swizzled
#pragma unroll
    for (int u = 0; u < 4; ++u) {
        const int rowl = wv * 8 + u * 2 + (lane >> 5);
        const int gsrc = (lane & 31) ^ (rowl & 7);
        gll16(Y + (size_t)(m0 + rowl) * 256 + gsrc * 8, &Al[wv * 8 + u * 2][0]);
    }
    stageB(0); stageB(1); stageB(2);   // total 10 insts in flight

#define G2S(t, NW) do { \
        VMW(NW); \
        __builtin_amdgcn_s_barrier(); \
        __builtin_amdgcn_sched_barrier(0); \
        comp(t); \
        if (((t) & 3) == 3) wout((t) >> 2); \
        __builtin_amdgcn_sched_barrier(0); \
        __builtin_amdgcn_s_barrier(); \
        if ((t) + 3 < 8) stageB((t) + 3); \
    } while (0)

    // t=0: VMW(4) retires A(4) + B0(2), leaves B1,B2
    G2S(0, 4); G2S(1, 4); G2S(2, 4); G2S(3, 4);
    G2S(4, 4); G2S(5, 4); G2S(6, 2); G2S(7, 0);
#undef G2S
}

// Fused per-(window,head) linear attention on blocked QKV layout.
__global__ __launch_bounds__(256) void kvy_kernel(
    const bf16_t* __restrict__ QKV,   // [24][32768][32]
    const int* __restrict__ offsets,
    const int* __restrict__ counts,
    bf16_t* __restrict__ Y)           // [32768,256] row-major
{
    const int w = blockIdx.x;
    const int h = blockIdx.y;
    const int is64 = (counts[1] == 0) ? 1 : 0;
    const int off = offsets[w << is64];
    const int tid = threadIdx.x;
    const int lane = tid & 63;
    const int wv = tid >> 6;

    __shared__ __align__(16) bf16_t KT[32 * 264];   // KT[c][t]
    __shared__ __align__(16) bf16_t VT[32 * 264];   // VT[d][t]
    __shared__ __align__(16) bf16_t KVT[32 * 40];   // KVT[d][c]
    __shared__ float sbuf[32];
    __shared__ float spart[32 * 8];
    __shared__ float zinv[WIN];

    // P0: stage K,V transposed (thread = token); fully coalesced 64B/token reads
    {
        const int t = tid;
        const bf16_t* kp = QKV + ((size_t)(8 + h) * M_TOK + off + t) * 32;
        const bf16_t* vp = QKV + ((size_t)(16 + h) * M_TOK + off + t) * 32;
        bf16_t ka[32], va[32];
#pragma unroll
        for (int u = 0; u < 4; ++u) {
            bf16x8 kk = *(const bf16x8*)(kp + u * 8);
            bf16x8 vvv = *(const bf16x8*)(vp + u * 8);
#pragma unroll
            for (int j = 0; j < 8; ++j) { ka[u * 8 + j] = kk[j]; va[u * 8 + j] = vvv[j]; }
        }
#pragma unroll
        for (int c = 0; c < 32; ++c) {
            KT[c * 264 + t] = ka[c];
            VT[c * 264 + t] = va[c];
        }
    }
    __syncthreads();

    // P1a: s partials
    {
        const int c = tid >> 3;
        const int tc = (tid & 7) * 32;
        float ps = 0.f;
#pragma unroll
        for (int u = 0; u < 4; ++u) {
            bf16x8 kk = *(const bf16x8*)(&KT[c * 264 + tc + u * 8]);
#pragma unroll
            for (int j = 0; j < 8; ++j) ps += (float)kk[j];
        }
        spart[c * 8 + (tid & 7)] = ps;
    }
    // P1b: KV = K^T V via MFMA (col-field->d, row-field->c); store KVT[d][c]
    {
        const int i = wv >> 1, j = wv & 1;
        const int r = lane & 15, q = lane >> 4;
        f32x4 acc = {};
#pragma unroll
        for (int ch = 0; ch < 8; ++ch) {
            bf16x8 af = *(const bf16x8*)(&KT[(i * 16 + r) * 264 + ch * 32 + q * 8]);
            bf16x8 bf_ = *(const bf16x8*)(&VT[(j * 16 + r) * 264 + ch * 32 + q * 8]);
            acc = __builtin_amdgcn_mfma_f32_16x16x32_bf16(af, bf_, acc, 0, 0, 0);
        }
        bf16x4 kv4;
#pragma unroll
        for (int reg = 0; reg < 4; ++reg) kv4[reg] = (bf16_t)acc[reg];
        *(bf16x4*)(&KVT[(j * 16 + r) * 40 + i * 16 + q * 4]) = kv4;
    }
    __syncthreads();
    if (tid < 32) {
        float s = 0.f;
#pragma unroll
        for (int u = 0; u < 8; ++u) s += spart[tid * 8 + u];
        sbuf[tid] = s;
    }
    __syncthreads();

    // P2: zinv[t]
    {
        const int t = tid;
        const bf16_t* qp = QKV + ((size_t)h * M_TOK + off + t) * 32;
        float z = 0.f;
#pragma unroll
        for (int u = 0; u < 4; ++u) {
            bf16x8 qq = *(const bf16x8*)(qp + u * 8);
#pragma unroll
            for (int j = 0; j < 8; ++j) z += (float)qq[j] * sbuf[u * 8 + j];
        }
        zinv[t] = 1.0f / (z + 1e-3f);
    }
    __syncthreads();

    // P3: y = (Q.KV)*zinv via swapped MFMA (col-field->t, row-field->d): bf16x4 stores
    {
        const int r = lane & 15, q = lane >> 4;
        bf16x8 b0 = *(const bf16x8*)(&KVT[(r) * 40 + q * 8]);        // d=r   (j=0)
        bf16x8 b1 = *(const bf16x8*)(&KVT[(16 + r) * 40 + q * 8]);   // d=16+r(j=1)
#pragma unroll
        for (int u = 0; u < 4; ++u) {
            const int mi = wv * 4 + u;
            const bf16_t* ap = QKV + ((size_t)h * M_TOK + off + mi * 16 + r) * 32 + q * 8;
            bf16x8 af = *(const bf16x8*)ap;
            f32x4 acc0 = {}, acc1 = {};
            acc0 = __builtin_amdgcn_mfma_f32_16x16x32_bf16(b0, af, acc0, 0, 0, 0);
            acc1 = __builtin_amdgcn_mfma_f32_16x16x32_bf16(b1, af, acc1, 0, 0, 0);
            const int tkn = mi * 16 + r;
            const float zi = zinv[tkn];
            bf16_t* yp = Y + (size_t)(off + tkn) * 256 + h * 32;
            bf16x4 o0, o1;
#pragma unroll
            for (int reg = 0; reg < 4; ++reg) {
                o0[reg] = (bf16_t)(acc0[reg] * zi);
                o1[reg] = (bf16_t)(acc1[reg] * zi);
            }
            *(bf16x4*)(yp + q * 4) = o0;
            *(bf16x4*)(yp + 16 + q * 4) = o1;
        }
    }
}

extern "C" void kernel_launch(void* const* d_in, const int* in_sizes, int n_in,
                              void* d_out, int out_size, void* d_ws, size_t ws_size,
                              hipStream_t stream) {
    const float* x      = (const float*)d_in[0];
    const float* w_qkv  = (const float*)d_in[1];
    const float* w_proj = (const float*)d_in[2];
    const float* b_proj = (const float*)d_in[3];
    const int*   offs   = (const int*)d_in[4];
    const int*   cnts   = (const int*)d_in[5];

    char* ws = (char*)d_ws;
    bf16_t* QKV = (bf16_t*)ws;                    // 24*32768*32*2 = 50331648 B
    bf16_t* Y   = (bf16_t*)(ws + 50331648);       // 16777216 B
    bf16_t* Wqb = (bf16_t*)(ws + 67108864);       //   393216 B
    bf16_t* Wpb = (bf16_t*)(ws + 67502080);       //   131072 B
    float*  out = (float*)d_out;

    // 0) weights fp32 -> bf16 (0.5 MB)
    wconv<<<256, 256, 0, stream>>>(w_qkv, w_proj, Wqb, Wpb);

    // 1) QKV gemm: 64-row panels, 2 blocks/CU, X read once
    gemm1_qkv<<<512, 512, 0, stream>>>(x, Wqb, QKV);

    // 2+3) fused per-(window,head) KV + normalize
    kvy_kernel<<<dim3(NWIN, 8), 256, 0, stream>>>(QKV, offs, cnts, Y);

    // 4) proj gemm: 64-row panels, 2 blocks/CU, Y read once
    gemm2_proj<<<512, 512, 0, stream>>>(Y, Wpb, b_proj, out);
}

// Round 8
// 133.196 us; speedup vs baseline: 1.1200x; 1.0369x over previous
//
#include <hip/hip_runtime.h>

typedef __bf16 bf16_t;
typedef bf16_t bf16x8 __attribute__((ext_vector_type(8)));
typedef bf16_t bf16x4 __attribute__((ext_vector_type(4)));
typedef float f32x4 __attribute__((ext_vector_type(4)));

#define M_TOK 32768
#define NWIN 128
#define WIN  256

typedef __attribute__((address_space(3))) void* as3p;
typedef const __attribute__((address_space(1))) void* as1p;

__device__ __forceinline__ void gll16(const void* g, void* l) {
    __builtin_amdgcn_global_load_lds((as1p)g, (as3p)l, 16, 0, 0);
}

#define VMW_(n) asm volatile("s_waitcnt vmcnt(" #n ")" ::: "memory")
#define VMW(n) VMW_(n)

#define MFMA16(b, a, c) __builtin_amdgcn_mfma_f32_16x16x32_bf16((b), (a), (c), 0, 0, 0)

// tiny fp32->bf16 weight convert (w_qkv 196608 + w_proj 65536 elems)
__global__ __launch_bounds__(256) void wconv(
    const float* __restrict__ wq, const float* __restrict__ wp,
    bf16_t* __restrict__ wqb, bf16_t* __restrict__ wpb)
{
    int i4 = (blockIdx.x * 256 + threadIdx.x) * 4;
    const float* s; bf16_t* dst; int idx;
    if (i4 < 196608) { s = wq; dst = wqb; idx = i4; }
    else             { s = wp; dst = wpb; idx = i4 - 196608; }
    f32x4 v = *(const f32x4*)(s + idx);
    bf16x4 o;
    o[0] = (bf16_t)v[0]; o[1] = (bf16_t)v[1]; o[2] = (bf16_t)v[2]; o[3] = (bf16_t)v[3];
    *(bf16x4*)(dst + idx) = o;
}

// Fused QKV-projection + windowed linear attention. One block = (window, 4 heads).
// Xb panel (256 tok x 256 ch, bf16, granule^row&7 swizzle) staged once; per head:
//   A: Q,K,V = X @ W^T (a-frags from Xb; K/V W-rows LDS-staged, Q W-rows global)
//   B: transpose-store relu(K),V -> KT/VT[c][t] (slot = (t>>3)^(c&7))
//   C: kv = K^T V via MFMA (waves 0-3) || s = colsum K (waves 4-7, shfl-reduce)
//   D: store relu(Q)->Ql[256][40], kv^T->kvb[32][32], s->f32
//   E: z[t] = Q.s (f32 VALU), zinv
//   F: y = (Q.kv)*zinv -> Y global
// MFMA convention (verified r5/r7): acc=mfma(b,a): a-frag lane(r,q)=A[mtile*16+r][q*8..],
// b-frag=B[ntile*16+r][q*8..], C: m=mtile*16+r (col-field), n=ntile*16+q*4+reg.
__global__ __launch_bounds__(512) void fused_attn(
    const float* __restrict__ X,
    const bf16_t* __restrict__ Wq,    // [768][256] bf16: rows 0-255 Q, 256-511 K, 512-767 V
    const int* __restrict__ offsets,
    const int* __restrict__ counts,
    bf16_t* __restrict__ Y)           // [32768][256] bf16
{
    __shared__ __align__(16) bf16_t Xb[65536];   // 128KB: [256][256] swizzled
    __shared__ __align__(16) bf16_t SCR[16384];  // 32KB: Wl / KT|VT / Ql|kvb|s|zinv

    // XCD-pairing: window's two head-halves -> same XCD (bids congruent mod 8)
    const int bid = blockIdx.x;
    const int w  = (bid & 7) * 16 + (bid >> 4);
    const int hh = (bid >> 3) & 1;
    const int is64 = (counts[1] == 0) ? 1 : 0;
    const int off = offsets[w << is64];
    const int tid = threadIdx.x;
    const int lane = tid & 63;
    const int wv = tid >> 6;
    const int r = lane & 15, q = lane >> 4;

    bf16_t* Wl  = SCR;                       // [64][256]: rows 0-31 K, 32-63 V (head-local)
    bf16_t* KT  = SCR;                       // [32][256] swizzled tokens
    bf16_t* VT  = SCR + 8192;
    bf16_t* Ql  = SCR;                       // [256][40]
    bf16_t* kvb = SCR + 10240;               // [32][32] = kv^T (rows d, cols c)
    float*  sfp = (float*)(SCR + 11264);     // [32]
    float*  zin = (float*)(SCR + 11328);     // [256]

    // stage Xb: 256x256 fp32 -> bf16, swizzled (r5/r7-verified pattern)
#pragma unroll 8
    for (int it = 0; it < 32; ++it) {
        const int L = it * 512 + tid;        // f32x4 index in [0,16384)
        const int row = L >> 6, col4 = L & 63;
        f32x4 v = *(const f32x4*)(X + (size_t)(off + row) * 256 + col4 * 4);
        bf16x4 o;
        o[0] = (bf16_t)v[0]; o[1] = (bf16_t)v[1]; o[2] = (bf16_t)v[2]; o[3] = (bf16_t)v[3];
        const int gs = (col4 >> 1) ^ (row & 7);
        *(bf16x4*)(Xb + row * 256 + gs * 8 + (col4 & 1) * 4) = o;
    }
    __syncthreads();

    for (int h4 = 0; h4 < 4; ++h4) {
        const int h = hh * 4 + h4;

        // stage W K/V rows for this head into Wl (pre-swizzled src; r7 gemm2 pattern)
#pragma unroll
        for (int u = 0; u < 4; ++u) {
            const int rowl = wv * 8 + u * 2 + (lane >> 5);   // 0..63
            const size_t grow = (size_t)((wv < 4 ? 256 : 480) + h * 32 + rowl);
            gll16(Wq + grow * 256 + ((lane & 31) ^ (rowl & 7)) * 8,
                  Wl + (wv * 8 + u * 2) * 256);
        }
        __syncthreads();   // Wl published (drains gll16)

        // phase A: Q,K,V accums (tokens wv*32..+31, all 32 head channels)
        f32x4 aQ[2][2] = {}, aK[2][2] = {}, aV[2][2] = {};
#pragma unroll
        for (int kch = 0; kch < 8; ++kch) {
            const int slot8 = (((kch * 4 + q) ^ (r & 7)) * 8);
            bf16x8 xa[2];
#pragma unroll
            for (int i2 = 0; i2 < 2; ++i2)
                xa[i2] = *(const bf16x8*)(Xb + (wv * 32 + i2 * 16 + r) * 256 + slot8);
#pragma unroll
            for (int ct = 0; ct < 2; ++ct) {
                bf16x8 bq = *(const bf16x8*)(Wq + (size_t)(h * 32 + ct * 16 + r) * 256
                                              + kch * 32 + q * 8);
                bf16x8 bk = *(const bf16x8*)(Wl + (ct * 16 + r) * 256 + slot8);
                bf16x8 bv = *(const bf16x8*)(Wl + (32 + ct * 16 + r) * 256 + slot8);
#pragma unroll
                for (int i2 = 0; i2 < 2; ++i2) {
                    aQ[i2][ct] = MFMA16(bq, xa[i2], aQ[i2][ct]);
                    aK[i2][ct] = MFMA16(bk, xa[i2], aK[i2][ct]);
                    aV[i2][ct] = MFMA16(bv, xa[i2], aV[i2][ct]);
                }
            }
        }
        __syncthreads();   // all waves done reading Wl

        // phase B: transpose-store relu(K),V -> KT/VT (overwrites Wl)
#pragma unroll
        for (int i2 = 0; i2 < 2; ++i2) {
            const int t = wv * 32 + i2 * 16 + r;
            const int gt = t >> 3;
#pragma unroll
            for (int ct = 0; ct < 2; ++ct)
#pragma unroll
                for (int reg = 0; reg < 4; ++reg) {
                    const int c = ct * 16 + q * 4 + reg;
                    const int ei = c * 256 + (gt ^ (c & 7)) * 8 + (t & 7);
                    KT[ei] = (bf16_t)fmaxf(aK[i2][ct][reg], 0.f);
                    VT[ei] = (bf16_t)aV[i2][ct][reg];
                }
        }
        __syncthreads();   // KT/VT published

        // phase C: kv-MFMA (waves 0-3) || s colsum (waves 4-7)
        f32x4 kva = {};
        float sc = 0.f;
        if (wv < 4) {
            const int ct = wv >> 1, dt = wv & 1;
#pragma unroll
            for (int kch = 0; kch < 8; ++kch) {
                const int slot8 = (((kch * 4 + q) ^ (r & 7)) * 8);
                bf16x8 ak = *(const bf16x8*)(KT + (ct * 16 + r) * 256 + slot8);
                bf16x8 bv = *(const bf16x8*)(VT + (dt * 16 + r) * 256 + slot8);
                kva = MFMA16(bv, ak, kva);       // kv[c=ct*16+r][d=dt*16+q*4+reg]
            }
        } else {
            const int tl = tid - 256;            // 0..255
            const int c = tl >> 3, p = tl & 7;
#pragma unroll
            for (int g = 0; g < 4; ++g) {        // granules p, p+8, p+16, p+24 (order-free)
                bf16x8 kk = *(const bf16x8*)(KT + c * 256 + (p + g * 8) * 8);
#pragma unroll
                for (int j = 0; j < 8; ++j) sc += (float)kk[j];
            }
            sc += __shfl_xor(sc, 1);
            sc += __shfl_xor(sc, 2);
            sc += __shfl_xor(sc, 4);
        }
        __syncthreads();   // KT/VT reads done; region may be overwritten

        // phase D: relu(Q)->Ql, kv^T->kvb, s->sfp
#pragma unroll
        for (int i2 = 0; i2 < 2; ++i2) {
            const int t = wv * 32 + i2 * 16 + r;
#pragma unroll
            for (int ct = 0; ct < 2; ++ct) {
                bf16x4 o;
#pragma unroll
                for (int reg = 0; reg < 4; ++reg)
                    o[reg] = (bf16_t)fmaxf(aQ[i2][ct][reg], 0.f);
                *(bf16x4*)(Ql + t * 40 + ct * 16 + q * 4) = o;
            }
        }
        if (wv < 4) {
            const int ct = wv >> 1, dt = wv & 1;
#pragma unroll
            for (int reg = 0; reg < 4; ++reg)
                kvb[(dt * 16 + q * 4 + reg) * 32 + ct * 16 + r] = (bf16_t)kva[reg];
        } else {
            const int tl = tid - 256;
            if ((tl & 7) == 0) sfp[tl >> 3] = sc;
        }
        __syncthreads();

        // phase E: z[t] = relu(Q).s in f32, zinv
        if (tid < 256) {
            float z = 0.f;
#pragma unroll
            for (int g = 0; g < 4; ++g) {
                bf16x8 qq = *(const bf16x8*)(Ql + tid * 40 + g * 8);
#pragma unroll
                for (int j = 0; j < 8; ++j) z += (float)qq[j] * sfp[g * 8 + j];
            }
            zin[tid] = 1.f / (z + 1e-3f);
        }
        __syncthreads();

        // phase F: y = (Q.kv)*zinv -> Y  (mirrors verified kvy P3)
        {
            bf16x8 bk0 = *(const bf16x8*)(kvb + r * 32 + q * 8);
            bf16x8 bk1 = *(const bf16x8*)(kvb + (16 + r) * 32 + q * 8);
#pragma unroll
            for (int i2 = 0; i2 < 2; ++i2) {
                const int t = wv * 32 + i2 * 16 + r;
                bf16x8 aq = *(const bf16x8*)(Ql + t * 40 + q * 8);
                f32x4 y0 = {}, y1 = {};
                y0 = MFMA16(bk0, aq, y0);
                y1 = MFMA16(bk1, aq, y1);
                const float zi = zin[t];
                bf16x4 o0, o1;
#pragma unroll
                for (int reg = 0; reg < 4; ++reg) {
                    o0[reg] = (bf16_t)(y0[reg] * zi);
                    o1[reg] = (bf16_t)(y1[reg] * zi);
                }
                bf16_t* yp = Y + (size_t)(off + t) * 256 + h * 32;
                *(bf16x4*)(yp + q * 4) = o0;
                *(bf16x4*)(yp + 16 + q * 4) = o1;
            }
        }
        __syncthreads();   // protect SCR before next head
    }
}

// GEMM2: Out = Y @ Wproj^T + b. 512 blocks x 512 thr, 64-row panel, 80KB LDS,
// 2 blocks/CU. Y panel (bf16) staged ONCE via gll16 pre-swizzled src;
// 2 n-blocks x 4 K-steps (BK=64).  [unchanged from round 7 — verified]
__global__ __launch_bounds__(512) void gemm2_proj(
    const bf16_t* __restrict__ Y,
    const bf16_t* __restrict__ Wb,
    const float* __restrict__ bias,
    float* __restrict__ Out)
{
    __shared__ __align__(16) bf16_t Al[64][256];      // 32KB persistent A panel
    __shared__ __align__(16) bf16_t Bs[3][128][64];   // 48KB B triple buffer

    const int tid = threadIdx.x;
    const int lane = tid & 63;
    const int wv = tid >> 6;
    const int wm = wv >> 2, wn = wv & 3;
    const int m0 = blockIdx.x * 64;
    const int r = lane & 15, q = lane >> 4;
    const int rl = lane >> 3, gsl = lane & 7;

    f32x4 acc[2][2] = {};

    auto stageB = [&](int t) {
        const int nb = t >> 2, kc = (t & 3) * 64;
#pragma unroll
        for (int u = 0; u < 2; ++u)
            gll16(Wb + (size_t)(nb * 128 + wv * 16 + u * 8 + rl) * 256 + kc + (gsl ^ rl) * 8,
                  &Bs[t % 3][wv * 16 + u * 8][0]);
    };

    auto comp = [&](int t) {
        const int buf = t % 3;
#pragma unroll
        for (int s = 0; s < 2; ++s) {
            const int kk = (t & 3) * 2 + s;
            bf16x8 a[2], b[2];
#pragma unroll
            for (int i = 0; i < 2; ++i)
                a[i] = *(const bf16x8*)((const bf16_t*)Al +
                        (wm * 32 + i * 16 + r) * 256 + ((kk * 4 + q) ^ (r & 7)) * 8);
#pragma unroll
            for (int j = 0; j < 2; ++j)
                b[j] = *(const bf16x8*)&Bs[buf][wn * 32 + j * 16 + r][((s * 4 + q) ^ (r & 7)) * 8];
#pragma unroll
            for (int i = 0; i < 2; ++i)
#pragma unroll
                for (int j = 0; j < 2; ++j)
                    acc[i][j] = MFMA16(b[j], a[i], acc[i][j]);
        }
    };

    auto wout = [&](int nb) {
#pragma unroll
        for (int i = 0; i < 2; ++i) {
            const int rowg = m0 + wm * 32 + i * 16 + r;
#pragma unroll
            for (int j = 0; j < 2; ++j) {
                const int n = nb * 128 + wn * 32 + j * 16 + q * 4;
                f32x4 bi = *(const f32x4*)(bias + n);
                f32x4 o;
#pragma unroll
                for (int reg = 0; reg < 4; ++reg) o[reg] = acc[i][j][reg] + bi[reg];
                *(f32x4*)&Out[(size_t)rowg * 256 + n] = o;
                acc[i][j] = (f32x4){0.f, 0.f, 0.f, 0.f};
            }
        }
    };

    // A panel staged once: 4 gll16/wave (1 inst = 2 rows of 512B); src pre-swizzled
#pragma unroll
    for (int u = 0; u < 4; ++u) {
        const int rowl = wv * 8 + u * 2 + (lane >> 5);
        const int gsrc = (lane & 31) ^ (rowl & 7);
        gll16(Y + (size_t)(m0 + rowl) * 256 + gsrc * 8, &Al[wv * 8 + u * 2][0]);
    }
    stageB(0); stageB(1); stageB(2);   // total 10 insts in flight

#define G2S(t, NW) do { \
        VMW(NW); \
        __builtin_amdgcn_s_barrier(); \
        __builtin_amdgcn_sched_barrier(0); \
        comp(t); \
        if (((t) & 3) == 3) wout((t) >> 2); \
        __builtin_amdgcn_sched_barrier(0); \
        __builtin_amdgcn_s_barrier(); \
        if ((t) + 3 < 8) stageB((t) + 3); \
    } while (0)

    // t=0: VMW(4) retires A(4) + B0(2), leaves B1,B2
    G2S(0, 4); G2S(1, 4); G2S(2, 4); G2S(3, 4);
    G2S(4, 4); G2S(5, 4); G2S(6, 2); G2S(7, 0);
#undef G2S
}

extern "C" void kernel_launch(void* const* d_in, const int* in_sizes, int n_in,
                              void* d_out, int out_size, void* d_ws, size_t ws_size,
                              hipStream_t stream) {
    const float* x      = (const float*)d_in[0];
    const float* w_qkv  = (const float*)d_in[1];
    const float* w_proj = (const float*)d_in[2];
    const float* b_proj = (const float*)d_in[3];
    const int*   offs   = (const int*)d_in[4];
    const int*   cnts   = (const int*)d_in[5];

    char* ws = (char*)d_ws;
    bf16_t* Y   = (bf16_t*)(ws + 50331648);       // 16777216 B
    bf16_t* Wqb = (bf16_t*)(ws + 67108864);       //   393216 B
    bf16_t* Wpb = (bf16_t*)(ws + 67502080);       //   131072 B
    float*  out = (float*)d_out;

    // 0) weights fp32 -> bf16 (0.5 MB)
    wconv<<<256, 256, 0, stream>>>(w_qkv, w_proj, Wqb, Wpb);

    // 1) fused QKV-projection + windowed attention (no QKV intermediate)
    fused_attn<<<256, 512, 0, stream>>>(x, Wqb, offs, cnts, Y);

    // 2) proj gemm: 64-row panels, 2 blocks/CU, Y read once
    gemm2_proj<<<512, 512, 0, stream>>>(Y, Wpb, b_proj, out);
}

// Round 9
// 129.555 us; speedup vs baseline: 1.1515x; 1.0281x over previous
//
#include <hip/hip_runtime.h>

typedef __bf16 bf16_t;
typedef bf16_t bf16x8 __attribute__((ext_vector_type(8)));
typedef bf16_t bf16x4 __attribute__((ext_vector_type(4)));
typedef float f32x4 __attribute__((ext_vector_type(4)));

#define M_TOK 32768
#define NWIN 128
#define WIN  256

typedef __attribute__((address_space(3))) void* as3p;
typedef const __attribute__((address_space(1))) void* as1p;

__device__ __forceinline__ void gll16(const void* g, void* l) {
    __builtin_amdgcn_global_load_lds((as1p)g, (as3p)l, 16, 0, 0);
}

__device__ __forceinline__ bf16x8 cvt8(f32x4 a, f32x4 b) {
    bf16x8 o;
    o[0] = (bf16_t)a[0]; o[1] = (bf16_t)a[1]; o[2] = (bf16_t)a[2]; o[3] = (bf16_t)a[3];
    o[4] = (bf16_t)b[0]; o[5] = (bf16_t)b[1]; o[6] = (bf16_t)b[2]; o[7] = (bf16_t)b[3];
    return o;
}

#define VMW_(n) asm volatile("s_waitcnt vmcnt(" #n ")" ::: "memory")
#define VMW(n) VMW_(n)
#define LGKM0 asm volatile("s_waitcnt lgkmcnt(0)" ::: "memory")

#define MFMA16(b, a, c) __builtin_amdgcn_mfma_f32_16x16x32_bf16((b), (a), (c), 0, 0, 0)

// tiny fp32->bf16 weight convert (w_qkv 196608 + w_proj 65536 elems)
__global__ __launch_bounds__(256) void wconv(
    const float* __restrict__ wq, const float* __restrict__ wp,
    bf16_t* __restrict__ wqb, bf16_t* __restrict__ wpb)
{
    int i4 = (blockIdx.x * 256 + threadIdx.x) * 4;
    const float* s; bf16_t* dst; int idx;
    if (i4 < 196608) { s = wq; dst = wqb; idx = i4; }
    else             { s = wp; dst = wpb; idx = i4 - 196608; }
    f32x4 v = *(const f32x4*)(s + idx);
    bf16x4 o;
    o[0] = (bf16_t)v[0]; o[1] = (bf16_t)v[1]; o[2] = (bf16_t)v[2]; o[3] = (bf16_t)v[3];
    *(bf16x4*)(dst + idx) = o;
}

// Fused QKV-projection + windowed linear attention. One block = (window, 4 heads).
// v2 (r9): X panel in REGISTERS (16 bf16x8/wave, loaded once, reused by 4 heads);
// W panel [96 rows: K 0-31, V 32-63, Q 64-95] double-buffered in LDS, stageW(h+1)
// issued after phase A(h) (counted-vmcnt protocol, r5/r7-verified); KT/VT and
// Ql/kvb/s/zinv in dedicated regions (phases B..F byte-identical to r8-verified).
// MFMA convention (verified r5/r7/r8): acc=mfma(b,a): a-frag lane(r,q)=A[m*16+r][q*8..],
// b-frag=B[n*16+r][q*8..], C: m-field=r (col), n-field=q*4+reg.
__global__ __launch_bounds__(512) void fused_attn(
    const float* __restrict__ X,
    const bf16_t* __restrict__ Wq,    // [768][256] bf16: rows 0-255 Q, 256-511 K, 512-767 V
    const int* __restrict__ offsets,
    const int* __restrict__ counts,
    bf16_t* __restrict__ Y)           // [32768][256] bf16
{
    __shared__ __align__(16) bf16_t Wl2[2][96 * 256];   // 96KB double-buffered W panel
    __shared__ __align__(16) bf16_t KT[32 * 256];       // 16KB (granule^c&7 swizzle)
    __shared__ __align__(16) bf16_t VT[32 * 256];       // 16KB
    __shared__ __align__(16) bf16_t Ql[256 * 40];       // 20KB
    __shared__ __align__(16) bf16_t kvb[32 * 32];       // 2KB  kv^T (rows d, cols c)
    __shared__ float sfp[32];
    __shared__ float zin[256];

    // XCD-pairing: window's two head-halves -> same XCD (bids congruent mod 8)
    const int bid = blockIdx.x;
    const int w  = (bid & 7) * 16 + (bid >> 4);
    const int hh = (bid >> 3) & 1;
    const int is64 = (counts[1] == 0) ? 1 : 0;
    const int off = offsets[w << is64];
    const int tid = threadIdx.x;
    const int lane = tid & 63;
    const int wv = tid >> 6;
    const int r = lane & 15, q = lane >> 4;

    // stage 96-row W panel for head h (pre-swizzled src granule, r7/r8 pattern)
    auto stageW = [&](int h, int buf) {
#pragma unroll
        for (int u = 0; u < 6; ++u) {
            const int rl = wv * 12 + u * 2 + (lane >> 5);   // 0..95, 2 rows/inst
            const int grow = (rl < 32 ? 256 + rl : (rl < 64 ? 480 + rl : rl - 64)) + h * 32;
            gll16(Wq + (size_t)grow * 256 + ((lane & 31) ^ (rl & 7)) * 8,
                  &Wl2[buf][(wv * 12 + u * 2) * 256]);
        }
    };

    // prologue: issue W(h0) DMA first, then X reg-loads (cvt waits don't drain gll16)
    stageW(hh * 4, 0);
    bf16x8 xr[2][8];   // X[t][kch*32+q*8..+7], t = wv*32 + i2*16 + r
#pragma unroll
    for (int i2 = 0; i2 < 2; ++i2) {
        const float* xp = X + (size_t)(off + wv * 32 + i2 * 16 + r) * 256 + q * 8;
#pragma unroll
        for (int kch = 0; kch < 8; ++kch) {
            f32x4 lo = *(const f32x4*)(xp + kch * 32);
            f32x4 hi = *(const f32x4*)(xp + kch * 32 + 4);
            xr[i2][kch] = cvt8(lo, hi);
        }
    }

    for (int h4 = 0; h4 < 4; ++h4) {
        const int h = hh * 4 + h4;
        const int buf = h4 & 1;
        VMW(0);                            // own stageW (+ own Y stores) drained
        __builtin_amdgcn_s_barrier();      // B1: Wl[buf] published
        __builtin_amdgcn_sched_barrier(0);
        const bf16_t* Wl = &Wl2[buf][0];

        // phase A: Q,K,V = X @ W^T, pure LDS b-frags + reg a-frags
        f32x4 aQ[2][2] = {}, aK[2][2] = {}, aV[2][2] = {};
#pragma unroll
        for (int kch = 0; kch < 8; ++kch) {
            const int slot8 = (((kch * 4 + q) ^ (r & 7)) * 8);
#pragma unroll
            for (int ct = 0; ct < 2; ++ct) {
                bf16x8 bk = *(const bf16x8*)(Wl + (ct * 16 + r) * 256 + slot8);
                bf16x8 bv = *(const bf16x8*)(Wl + (32 + ct * 16 + r) * 256 + slot8);
                bf16x8 bq = *(const bf16x8*)(Wl + (64 + ct * 16 + r) * 256 + slot8);
#pragma unroll
                for (int i2 = 0; i2 < 2; ++i2) {
                    aQ[i2][ct] = MFMA16(bq, xr[i2][kch], aQ[i2][ct]);
                    aK[i2][ct] = MFMA16(bk, xr[i2][kch], aK[i2][ct]);
                    aV[i2][ct] = MFMA16(bv, xr[i2][kch], aV[i2][ct]);
                }
            }
        }
        // prefetch next head's W panel; hides under phases B..F
        if (h4 < 3) stageW(h + 1, buf ^ 1);

        // phase B: transpose-store relu(K),V -> KT/VT (r8-verbatim)
#pragma unroll
        for (int i2 = 0; i2 < 2; ++i2) {
            const int t = wv * 32 + i2 * 16 + r;
            const int gt = t >> 3;
#pragma unroll
            for (int ct = 0; ct < 2; ++ct)
#pragma unroll
                for (int reg = 0; reg < 4; ++reg) {
                    const int c = ct * 16 + q * 4 + reg;
                    const int ei = c * 256 + (gt ^ (c & 7)) * 8 + (t & 7);
                    KT[ei] = (bf16_t)fmaxf(aK[i2][ct][reg], 0.f);
                    VT[ei] = (bf16_t)aV[i2][ct][reg];
                }
        }
        LGKM0;                             // publish ds_writes, keep gll16 in flight
        __builtin_amdgcn_s_barrier();      // B2: KT/VT published
        __builtin_amdgcn_sched_barrier(0);

        // phase C: kv-MFMA (waves 0-3) || s colsum (waves 4-7)  (r8-verbatim)
        f32x4 kva = {};
        float sc = 0.f;
        if (wv < 4) {
            const int ct = wv >> 1, dt = wv & 1;
#pragma unroll
            for (int kch = 0; kch < 8; ++kch) {
                const int slot8 = (((kch * 4 + q) ^ (r & 7)) * 8);
                bf16x8 ak = *(const bf16x8*)(KT + (ct * 16 + r) * 256 + slot8);
                bf16x8 bv2 = *(const bf16x8*)(VT + (dt * 16 + r) * 256 + slot8);
                kva = MFMA16(bv2, ak, kva);     // kv[c=ct*16+r][d=dt*16+q*4+reg]
            }
        } else {
            const int tl = tid - 256;
            const int c = tl >> 3, p = tl & 7;
#pragma unroll
            for (int g = 0; g < 4; ++g) {       // all 32 granules, order-free sum
                bf16x8 kk = *(const bf16x8*)(KT + c * 256 + (p + g * 8) * 8);
#pragma unroll
                for (int j = 0; j < 8; ++j) sc += (float)kk[j];
            }
            sc += __shfl_xor(sc, 1);
            sc += __shfl_xor(sc, 2);
            sc += __shfl_xor(sc, 4);
        }

        // phase D: relu(Q)->Ql, kv^T->kvb, s->sfp (r8-verbatim; dedicated regions)
#pragma unroll
        for (int i2 = 0; i2 < 2; ++i2) {
            const int t = wv * 32 + i2 * 16 + r;
#pragma unroll
            for (int ct = 0; ct < 2; ++ct) {
                bf16x4 o;
#pragma unroll
                for (int reg = 0; reg < 4; ++reg)
                    o[reg] = (bf16_t)fmaxf(aQ[i2][ct][reg], 0.f);
                *(bf16x4*)(Ql + t * 40 + ct * 16 + q * 4) = o;
            }
        }
        if (wv < 4) {
            const int ct = wv >> 1, dt = wv & 1;
#pragma unroll
            for (int reg = 0; reg < 4; ++reg)
                kvb[(dt * 16 + q * 4 + reg) * 32 + ct * 16 + r] = (bf16_t)kva[reg];
        } else {
            const int tl = tid - 256;
            if ((tl & 7) == 0) sfp[tl >> 3] = sc;
        }
        LGKM0;
        __builtin_amdgcn_s_barrier();      // B3: Ql/kvb/sfp published
        __builtin_amdgcn_sched_barrier(0);

        // phase E: z[t] = relu(Q).s in f32, zinv (r8-verbatim)
        if (tid < 256) {
            float z = 0.f;
#pragma unroll
            for (int g = 0; g < 4; ++g) {
                bf16x8 qq = *(const bf16x8*)(Ql + tid * 40 + g * 8);
#pragma unroll
                for (int j = 0; j < 8; ++j) z += (float)qq[j] * sfp[g * 8 + j];
            }
            zin[tid] = 1.f / (z + 1e-3f);
        }
        LGKM0;
        __builtin_amdgcn_s_barrier();      // B4: zin published
        __builtin_amdgcn_sched_barrier(0);

        // phase F: y = (Q.kv)*zinv -> Y (r8-verbatim)
        {
            bf16x8 bk0 = *(const bf16x8*)(kvb + r * 32 + q * 8);
            bf16x8 bk1 = *(const bf16x8*)(kvb + (16 + r) * 32 + q * 8);
#pragma unroll
            for (int i2 = 0; i2 < 2; ++i2) {
                const int t = wv * 32 + i2 * 16 + r;
                bf16x8 aq = *(const bf16x8*)(Ql + t * 40 + q * 8);
                f32x4 y0 = {}, y1 = {};
                y0 = MFMA16(bk0, aq, y0);
                y1 = MFMA16(bk1, aq, y1);
                const float zi = zin[t];
                bf16x4 o0, o1;
#pragma unroll
                for (int reg = 0; reg < 4; ++reg) {
                    o0[reg] = (bf16_t)(y0[reg] * zi);
                    o1[reg] = (bf16_t)(y1[reg] * zi);
                }
                bf16_t* yp = Y + (size_t)(off + t) * 256 + h * 32;
                *(bf16x4*)(yp + q * 4) = o0;
                *(bf16x4*)(yp + 16 + q * 4) = o1;
            }
        }
        // no end barrier: next writes to Ql/kvb/zin are >=2 barriers away (B1,B2)
    }
}

// GEMM2: Out = Y @ Wproj^T + b. 512 blocks x 512 thr, 64-row panel, 80KB LDS,
// 2 blocks/CU. Y panel (bf16) staged ONCE via gll16 pre-swizzled src;
// 2 n-blocks x 4 K-steps (BK=64).  [unchanged from r7/r8 — verified, ~6us]
__global__ __launch_bounds__(512) void gemm2_proj(
    const bf16_t* __restrict__ Y,
    const bf16_t* __restrict__ Wb,
    const float* __restrict__ bias,
    float* __restrict__ Out)
{
    __shared__ __align__(16) bf16_t Al[64][256];      // 32KB persistent A panel
    __shared__ __align__(16) bf16_t Bs[3][128][64];   // 48KB B triple buffer

    const int tid = threadIdx.x;
    const int lane = tid & 63;
    const int wv = tid >> 6;
    const int wm = wv >> 2, wn = wv & 3;
    const int m0 = blockIdx.x * 64;
    const int r = lane & 15, q = lane >> 4;
    const int rl = lane >> 3, gsl = lane & 7;

    f32x4 acc[2][2] = {};

    auto stageB = [&](int t) {
        const int nb = t >> 2, kc = (t & 3) * 64;
#pragma unroll
        for (int u = 0; u < 2; ++u)
            gll16(Wb + (size_t)(nb * 128 + wv * 16 + u * 8 + rl) * 256 + kc + (gsl ^ rl) * 8,
                  &Bs[t % 3][wv * 16 + u * 8][0]);
    };

    auto comp = [&](int t) {
        const int buf = t % 3;
#pragma unroll
        for (int s = 0; s < 2; ++s) {
            const int kk = (t & 3) * 2 + s;
            bf16x8 a[2], b[2];
#pragma unroll
            for (int i = 0; i < 2; ++i)
                a[i] = *(const bf16x8*)((const bf16_t*)Al +
                        (wm * 32 + i * 16 + r) * 256 + ((kk * 4 + q) ^ (r & 7)) * 8);
#pragma unroll
            for (int j = 0; j < 2; ++j)
                b[j] = *(const bf16x8*)&Bs[buf][wn * 32 + j * 16 + r][((s * 4 + q) ^ (r & 7)) * 8];
#pragma unroll
            for (int i = 0; i < 2; ++i)
#pragma unroll
                for (int j = 0; j < 2; ++j)
                    acc[i][j] = MFMA16(b[j], a[i], acc[i][j]);
        }
    };

    auto wout = [&](int nb) {
#pragma unroll
        for (int i = 0; i < 2; ++i) {
            const int rowg = m0 + wm * 32 + i * 16 + r;
#pragma unroll
            for (int j = 0; j < 2; ++j) {
                const int n = nb * 128 + wn * 32 + j * 16 + q * 4;
                f32x4 bi = *(const f32x4*)(bias + n);
                f32x4 o;
#pragma unroll
                for (int reg = 0; reg < 4; ++reg) o[reg] = acc[i][j][reg] + bi[reg];
                *(f32x4*)&Out[(size_t)rowg * 256 + n] = o;
                acc[i][j] = (f32x4){0.f, 0.f, 0.f, 0.f};
            }
        }
    };

    // A panel staged once: 4 gll16/wave (1 inst = 2 rows of 512B); src pre-swizzled
#pragma unroll
    for (int u = 0; u < 4; ++u) {
        const int rowl = wv * 8 + u * 2 + (lane >> 5);
        const int gsrc = (lane & 31) ^ (rowl & 7);
        gll16(Y + (size_t)(m0 + rowl) * 256 + gsrc * 8, &Al[wv * 8 + u * 2][0]);
    }
    stageB(0); stageB(1); stageB(2);   // total 10 insts in flight

#define G2S(t, NW) do { \
        VMW(NW); \
        __builtin_amdgcn_s_barrier(); \
        __builtin_amdgcn_sched_barrier(0); \
        comp(t); \
        if (((t) & 3) == 3) wout((t) >> 2); \
        __builtin_amdgcn_sched_barrier(0); \
        __builtin_amdgcn_s_barrier(); \
        if ((t) + 3 < 8) stageB((t) + 3); \
    } while (0)

    // t=0: VMW(4) retires A(4) + B0(2), leaves B1,B2
    G2S(0, 4); G2S(1, 4); G2S(2, 4); G2S(3, 4);
    G2S(4, 4); G2S(5, 4); G2S(6, 2); G2S(7, 0);
#undef G2S
}

extern "C" void kernel_launch(void* const* d_in, const int* in_sizes, int n_in,
                              void* d_out, int out_size, void* d_ws, size_t ws_size,
                              hipStream_t stream) {
    const float* x      = (const float*)d_in[0];
    const float* w_qkv  = (const float*)d_in[1];
    const float* w_proj = (const float*)d_in[2];
    const float* b_proj = (const float*)d_in[3];
    const int*   offs   = (const int*)d_in[4];
    const int*   cnts   = (const int*)d_in[5];

    char* ws = (char*)d_ws;
    bf16_t* Y   = (bf16_t*)(ws + 50331648);       // 16777216 B
    bf16_t* Wqb = (bf16_t*)(ws + 67108864);       //   393216 B
    bf16_t* Wpb = (bf16_t*)(ws + 67502080);       //   131072 B
    float*  out = (float*)d_out;

    // 0) weights fp32 -> bf16 (0.5 MB)
    wconv<<<256, 256, 0, stream>>>(w_qkv, w_proj, Wqb, Wpb);

    // 1) fused QKV-projection + windowed attention (X in regs, W double-buffered)
    fused_attn<<<256, 512, 0, stream>>>(x, Wqb, offs, cnts, Y);

    // 2) proj gemm: 64-row panels, 2 blocks/CU, Y read once
    gemm2_proj<<<512, 512, 0, stream>>>(Y, Wpb, b_proj, out);
}